// Round 5
// baseline (430.649 us; speedup 1.0000x reference)
//
#include <hip/hip_runtime.h>
#include <math.h>

#define NNODES 50000
#define NEDGES 800000
#define FDIM 128
#define NBLK_SCAN 196   // ceil(50000/256)
#define GGRID 391       // ceil(50000/128)
#define FILLB 3125      // ceil(800000/256)

typedef unsigned short ushortT;
typedef unsigned int uintT;

__device__ __forceinline__ float gelu_erf(float x){
    return 0.5f * x * (1.0f + erff(x * 0.70710678118654752f));
}
// bf16 helpers: packed ushort2 in a uint
__device__ __forceinline__ float bflo(uintT u){ return __uint_as_float(u << 16); }
__device__ __forceinline__ float bfhi(uintT u){ return __uint_as_float(u & 0xFFFF0000u); }
__device__ __forceinline__ ushortT f2bf(float f){
    uintT u = __float_as_uint(f);
    return (ushortT)((u + 0x7FFFu + ((u >> 16) & 1u)) >> 16);   // RNE
}

// ---------------- CSR build ----------------
__global__ void k_zero_cnt(int* __restrict__ cnt){
    int i = blockIdx.x*blockDim.x + threadIdx.x;
    if (i < NNODES) cnt[i] = 0;
}
__global__ void k_hist(const int* __restrict__ ei, int* __restrict__ cnt){
    int e = blockIdx.x*blockDim.x + threadIdx.x;
    if (e < NEDGES) atomicAdd(&cnt[ei[NEDGES + e]], 1);
}
__global__ __launch_bounds__(256) void k_blocksum(const int* __restrict__ cnt, int* __restrict__ bsum){
    __shared__ int sm[256];
    int t = threadIdx.x;
    int i = blockIdx.x*256 + t;
    sm[t] = (i < NNODES) ? cnt[i] : 0;
    __syncthreads();
    for (int off = 128; off > 0; off >>= 1){
        if (t < off) sm[t] += sm[t+off];
        __syncthreads();
    }
    if (t == 0) bsum[blockIdx.x] = sm[0];
}
__global__ __launch_bounds__(256) void k_scanblocks(int* __restrict__ bsum){
    __shared__ int sm[256];
    int t = threadIdx.x;
    int v = (t < NBLK_SCAN) ? bsum[t] : 0;
    sm[t] = v;
    __syncthreads();
    for (int off = 1; off < 256; off <<= 1){
        int tv = (t >= off) ? sm[t-off] : 0;
        __syncthreads();
        sm[t] += tv;
        __syncthreads();
    }
    if (t < NBLK_SCAN) bsum[t] = sm[t] - v;   // exclusive
}
__global__ __launch_bounds__(256) void k_scanfinal(const int* __restrict__ cnt,
                                                   const int* __restrict__ bsum,
                                                   int* __restrict__ offs,
                                                   int* __restrict__ cursor,
                                                   float* __restrict__ dinv){
    __shared__ int sm[256];
    int t = threadIdx.x;
    int i = blockIdx.x*256 + t;
    int v = (i < NNODES) ? cnt[i] : 0;
    sm[t] = v;
    __syncthreads();
    for (int off = 1; off < 256; off <<= 1){
        int tv = (t >= off) ? sm[t-off] : 0;
        __syncthreads();
        sm[t] += tv;
        __syncthreads();
    }
    int excl = sm[t] - v + bsum[blockIdx.x];
    if (i < NNODES){
        offs[i] = excl;
        cursor[i] = excl;
        dinv[i] = rsqrtf((float)(v + 1));   // +1 self loop
    }
    if (i == 0) offs[NNODES] = NEDGES;
}

// ---------------- GEMM body [nrows,128] x [128,128] ----------------
// 128x128 tile, 256 threads, 8x8 microtile.
// OUTMODE 0: fp32 row-major out, +bias +gelu (post-conv MLP layer)
// OUTMODE 1: bf16 chunk-transposed out, scaled by dinv[row] (Ys = dinv_r * Y_r)
template<int OUTMODE>
__device__ __forceinline__ void gemm128_body(const float* __restrict__ A,
                                             const float* __restrict__ W,
                                             const float* __restrict__ scale,
                                             const float* __restrict__ bias,
                                             const float* __restrict__ dinv,
                                             void* __restrict__ Yout, int bid){
    __shared__ float As[128*40];
    __shared__ float Ws[32*132];
    int t = threadIdx.x;
    int tx = t & 15;
    int ty = t >> 4;
    int row0 = bid * 128;

    float acc[8][8];
    #pragma unroll
    for (int a=0;a<8;a++)
        #pragma unroll
        for (int b=0;b<8;b++) acc[a][b]=0.f;

    for (int k0 = 0; k0 < 128; k0 += 32){
        #pragma unroll
        for (int p=0;p<4;p++){
            int l = p*256 + t;
            int r = l >> 3;
            int c4 = l & 7;
            int gr = row0 + r;
            float4 v = make_float4(0.f,0.f,0.f,0.f);
            if (gr < NNODES) v = *(const float4*)&A[(size_t)gr*FDIM + k0 + c4*4];
            if (scale){
                float4 s = *(const float4*)&scale[k0 + c4*4];
                v.x*=s.x; v.y*=s.y; v.z*=s.z; v.w*=s.w;
            }
            *(float4*)&As[r*40 + c4*4] = v;
        }
        #pragma unroll
        for (int p=0;p<4;p++){
            int l = p*256 + t;
            int kk = l >> 5;
            int j4 = l & 31;
            float4 v = *(const float4*)&W[(size_t)(k0+kk)*FDIM + j4*4];
            *(float4*)&Ws[kk*132 + j4*4] = v;
        }
        __syncthreads();
        #pragma unroll
        for (int kk = 0; kk < 32; kk += 4){
            float4 af[8];
            #pragma unroll
            for (int rr=0;rr<8;rr++){
                int r = ty + 16*rr;
                af[rr] = *(const float4*)&As[r*40 + kk];
            }
            #pragma unroll
            for (int kv=0;kv<4;kv++){
                const float4 w0 = *(const float4*)&Ws[(kk+kv)*132 + tx*4];
                const float4 w1 = *(const float4*)&Ws[(kk+kv)*132 + 64 + tx*4];
                #pragma unroll
                for (int rr=0;rr<8;rr++){
                    const float av = (kv==0) ? af[rr].x : (kv==1) ? af[rr].y :
                                     (kv==2) ? af[rr].z : af[rr].w;
                    acc[rr][0]=fmaf(av,w0.x,acc[rr][0]);
                    acc[rr][1]=fmaf(av,w0.y,acc[rr][1]);
                    acc[rr][2]=fmaf(av,w0.z,acc[rr][2]);
                    acc[rr][3]=fmaf(av,w0.w,acc[rr][3]);
                    acc[rr][4]=fmaf(av,w1.x,acc[rr][4]);
                    acc[rr][5]=fmaf(av,w1.y,acc[rr][5]);
                    acc[rr][6]=fmaf(av,w1.z,acc[rr][6]);
                    acc[rr][7]=fmaf(av,w1.w,acc[rr][7]);
                }
            }
        }
        __syncthreads();
    }
    float4 bv0 = make_float4(0.f,0.f,0.f,0.f), bv1 = bv0;
    if (OUTMODE == 0 && bias){
        bv0 = *(const float4*)&bias[tx*4];
        bv1 = *(const float4*)&bias[64 + tx*4];
    }
    #pragma unroll
    for (int rr=0;rr<8;rr++){
        int row = row0 + ty + 16*rr;
        if (row < NNODES){
            float4 v0, v1;
            v0.x=acc[rr][0]; v0.y=acc[rr][1]; v0.z=acc[rr][2]; v0.w=acc[rr][3];
            v1.x=acc[rr][4]; v1.y=acc[rr][5]; v1.z=acc[rr][6]; v1.w=acc[rr][7];
            if (OUTMODE == 1){
                float dv = dinv[row];
                v0.x*=dv; v0.y*=dv; v0.z*=dv; v0.w*=dv;
                v1.x*=dv; v1.y*=dv; v1.z*=dv; v1.w*=dv;
                ushortT* Yb = (ushortT*)Yout;
                ushort4 o0, o1;
                o0.x=f2bf(v0.x); o0.y=f2bf(v0.y); o0.z=f2bf(v0.z); o0.w=f2bf(v0.w);
                o1.x=f2bf(v1.x); o1.y=f2bf(v1.y); o1.z=f2bf(v1.z); o1.w=f2bf(v1.w);
                int jA = tx*4;           // 0..60 -> chunks 0,1
                int cA = jA >> 5, oA = jA & 31;
                int jB = 64 + tx*4;      // 64..124 -> chunks 2,3
                int cB = jB >> 5, oB = jB & 31;
                *(ushort4*)&Yb[((size_t)cA*NNODES + row)*32 + oA] = o0;
                *(ushort4*)&Yb[((size_t)cB*NNODES + row)*32 + oB] = o1;
            } else {
                v0.x=gelu_erf(v0.x+bv0.x); v0.y=gelu_erf(v0.y+bv0.y);
                v0.z=gelu_erf(v0.z+bv0.z); v0.w=gelu_erf(v0.w+bv0.w);
                v1.x=gelu_erf(v1.x+bv1.x); v1.y=gelu_erf(v1.y+bv1.y);
                v1.z=gelu_erf(v1.z+bv1.z); v1.w=gelu_erf(v1.w+bv1.w);
                float* Yf = (float*)Yout;
                *(float4*)&Yf[(size_t)row*FDIM + tx*4] = v0;
                *(float4*)&Yf[(size_t)row*FDIM + 64 + tx*4] = v1;
            }
        }
    }
}

// GEMM wrappers
__global__ __launch_bounds__(256) void k_gemm_t(const float* __restrict__ A,
                                                const float* __restrict__ W,
                                                const float* __restrict__ scale,
                                                const float* __restrict__ dinv,
                                                ushortT* __restrict__ Yt){
    gemm128_body<1>(A, W, scale, nullptr, dinv, (void*)Yt, blockIdx.x);
}
__global__ __launch_bounds__(256) void k_gemm_f(const float* __restrict__ A,
                                                const float* __restrict__ W,
                                                const float* __restrict__ bias,
                                                float* __restrict__ Y){
    gemm128_body<0>(A, W, nullptr, bias, nullptr, (void*)Y, blockIdx.x);
}

// Fused: layer-1 GEMM (blocks [0,GGRID)) + CSR fill (blocks [GGRID, GGRID+FILLB))
__global__ __launch_bounds__(256) void k_gemm1_fill(const float* __restrict__ x,
                                                    const float* __restrict__ W1,
                                                    const float* __restrict__ imp,
                                                    const float* __restrict__ dinv,
                                                    ushortT* __restrict__ Yt,
                                                    const int* __restrict__ ei,
                                                    int* __restrict__ cursor,
                                                    ushortT* __restrict__ csr2){
    int bid = blockIdx.x;
    if (bid < GGRID){
        gemm128_body<1>(x, W1, imp, nullptr, dinv, (void*)Yt, bid);
    } else {
        int e = (bid - GGRID)*256 + threadIdx.x;
        if (e < NEDGES){
            int r = ei[e];
            int c = ei[NEDGES + e];
            int pos = atomicAdd(&cursor[c], 1);
            csr2[pos] = (ushortT)r;
        }
    }
}

// ---------------- sharded aggregation ----------------
// chunk = blockIdx&3 (32 feats = one 64B line per node); 16 nodes/block, 16 lanes/node.
// out[c] = dinv_c * (Ys[c] + sum Ys[r]) + bias, gelu.
__global__ __launch_bounds__(256) void k_aggregate(const ushortT* __restrict__ Yt,
                                                   const float* __restrict__ dinv,
                                                   const int* __restrict__ offs,
                                                   const ushortT* __restrict__ csr2,
                                                   const float* __restrict__ bias,
                                                   float* __restrict__ Hout){
    int bid = blockIdx.x;
    int chunk = bid & 3;
    int node = (bid >> 2) * 16 + (threadIdx.x >> 4);
    int lane = threadIdx.x & 15;
    const uintT* Yc = (const uintT*)Yt + (size_t)chunk * NNODES * 16;

    uintT a0 = Yc[node*16 + lane];
    float2 acc;
    acc.x = bflo(a0);
    acc.y = bfhi(a0);
    int e0 = offs[node], e1 = offs[node+1];
    int e = e0;
    for (; e + 3 < e1; e += 4){
        int r0 = csr2[e+0];
        int r1 = csr2[e+1];
        int r2 = csr2[e+2];
        int r3 = csr2[e+3];
        uintT q0 = Yc[r0*16 + lane];
        uintT q1 = Yc[r1*16 + lane];
        uintT q2 = Yc[r2*16 + lane];
        uintT q3 = Yc[r3*16 + lane];
        acc.x += bflo(q0); acc.y += bfhi(q0);
        acc.x += bflo(q1); acc.y += bfhi(q1);
        acc.x += bflo(q2); acc.y += bfhi(q2);
        acc.x += bflo(q3); acc.y += bfhi(q3);
    }
    for (; e < e1; e++){
        int r = csr2[e];
        uintT q = Yc[r*16 + lane];
        acc.x += bflo(q); acc.y += bfhi(q);
    }
    float dc = dinv[node];
    float2 bv = ((const float2*)bias)[chunk*16 + lane];
    acc.x = gelu_erf(fmaf(dc, acc.x, bv.x));
    acc.y = gelu_erf(fmaf(dc, acc.y, bv.y));
    float* dst = &Hout[(size_t)node*FDIM + chunk*32 + lane*2];
    __builtin_nontemporal_store(acc.x, dst);
    __builtin_nontemporal_store(acc.y, dst+1);
}

// ---------------- final GEMM [nrows,128] x [128,16] + bias ----------------
__global__ __launch_bounds__(256) void k_gemm16(const float* __restrict__ A,
                                                const float* __restrict__ W,
                                                const float* __restrict__ bias,
                                                float* __restrict__ out){
    __shared__ float Hs[16][132];
    __shared__ float Ws2[128][16];
    int row0 = blockIdx.x * 16;
    int t = threadIdx.x;
    #pragma unroll
    for (int p=0;p<8;p++){
        int lin = p*256 + t;
        int r = lin >> 7, c = lin & 127;
        Hs[r][c] = A[(row0+r)*FDIM + c];
    }
    #pragma unroll
    for (int p=0;p<8;p++){
        int lin = p*256 + t;
        Ws2[lin>>4][lin&15] = W[lin];
    }
    __syncthreads();
    int il = t >> 4, j = t & 15;
    float acc = bias[j];
    #pragma unroll
    for (int k=0;k<FDIM;k++) acc = fmaf(Hs[il][k], Ws2[k][j], acc);
    out[(row0+il)*16 + j] = acc;
}

extern "C" void kernel_launch(void* const* d_in, const int* in_sizes, int n_in,
                              void* d_out, int out_size, void* d_ws, size_t ws_size,
                              hipStream_t stream) {
    const float* x    = (const float*)d_in[0];
    const int*   ei   = (const int*)d_in[1];
    const float* imp  = (const float*)d_in[2];
    const float* W1   = (const float*)d_in[3];
    const float* b1   = (const float*)d_in[4];
    const float* W2   = (const float*)d_in[5];
    const float* b2   = (const float*)d_in[6];
    const float* W3   = (const float*)d_in[7];
    const float* b3   = (const float*)d_in[8];
    const float* lw1  = (const float*)d_in[9];
    const float* lb1  = (const float*)d_in[10];
    const float* lw2  = (const float*)d_in[11];
    const float* lb2  = (const float*)d_in[12];
    float* out = (float*)d_out;

    // workspace layout (units of 4 bytes)
    int*   cnt    = (int*)d_ws;                          // 50000
    int*   offs   = (int*)d_ws + 50176;                  // 50001
    int*   cursor = (int*)d_ws + 100480;                 // 50000
    int*   bsum   = (int*)d_ws + 150528;                 // 256
    float* dinv   = (float*)d_ws + 150784;               // 50000
    ushortT* csr2 = (ushortT*)((int*)d_ws + 200960);     // 800000 ushort (1.6 MB)
    ushortT* bufYt= (ushortT*)((int*)d_ws + 600960);     // 50000*128 bf16 transposed (12.8 MB)
    float* bufY   = (float*)d_ws + 600960;               // alias: fp32 lw1 output (25.6 MB; used after Yt dead)
    float* bufH   = (float*)d_ws + 7000960;              // N*128 fp32 (25.6 MB)

    dim3 B(256);
    // ---- CSR build prologue ----
    k_zero_cnt  <<<NBLK_SCAN, B, 0, stream>>>(cnt);
    k_hist      <<<FILLB, B, 0, stream>>>(ei, cnt);
    k_blocksum  <<<NBLK_SCAN, B, 0, stream>>>(cnt, bsum);
    k_scanblocks<<<1, B, 0, stream>>>(bsum);
    k_scanfinal <<<NBLK_SCAN, B, 0, stream>>>(cnt, bsum, offs, cursor, dinv);

    // ---- layer-1 GEMM fused with CSR fill ----
    k_gemm1_fill<<<GGRID + FILLB, B, 0, stream>>>(x, W1, imp, dinv, bufYt, ei, cursor, csr2);
    k_aggregate <<<(NNODES/16)*4, B, 0, stream>>>(bufYt, dinv, offs, csr2, b1, bufH);

    // ---- layers 2,3 ----
    k_gemm_t    <<<GGRID, B, 0, stream>>>(bufH, W2, nullptr, dinv, bufYt);
    k_aggregate <<<(NNODES/16)*4, B, 0, stream>>>(bufYt, dinv, offs, csr2, b2, bufH);
    k_gemm_t    <<<GGRID, B, 0, stream>>>(bufH, W3, nullptr, dinv, bufYt);
    k_aggregate <<<(NNODES/16)*4, B, 0, stream>>>(bufYt, dinv, offs, csr2, b3, bufH);

    // ---- h = gelu(h @ lw1 + lb1) ----
    k_gemm_f<<<GGRID, B, 0, stream>>>(bufH, lw1, lb1, bufY);
    // ---- out = h @ lw2 + lb2 ----
    k_gemm16<<<NNODES/16, B, 0, stream>>>(bufY, lw2, lb2, out);
}

// Round 6
// 423.774 us; speedup vs baseline: 1.0162x; 1.0162x over previous
//
#include <hip/hip_runtime.h>
#include <math.h>

#define NNODES 50000
#define NEDGES 800000
#define FDIM 128
#define NBLK_SCAN 196   // ceil(50000/256)
#define GGRID 391       // ceil(50000/128)
#define NBUCKET 64
#define BSPAN 782       // nodes per bucket: 64*782 = 50048 >= 50000
#define BCAP 16384      // capacity per bucket (expect ~12512)
#define ABLK 128        // pass-A workgroups
#define EPW 6250        // edges per pass-A wg (128*6250 = 800000)

typedef unsigned short ushortT;
typedef unsigned int uintT;

__device__ __forceinline__ float gelu_erf(float x){
    return 0.5f * x * (1.0f + erff(x * 0.70710678118654752f));
}
// bf16 helpers: packed ushort2 in a uint
__device__ __forceinline__ float bflo(uintT u){ return __uint_as_float(u << 16); }
__device__ __forceinline__ float bfhi(uintT u){ return __uint_as_float(u & 0xFFFF0000u); }
__device__ __forceinline__ ushortT f2bf(float f){
    uintT u = __float_as_uint(f);
    return (ushortT)((u + 0x7FFFu + ((u >> 16) & 1u)) >> 16);   // RNE
}

// ---------------- CSR build ----------------
__global__ void k_zero(int* __restrict__ cnt, int* __restrict__ gcur){
    int i = blockIdx.x*blockDim.x + threadIdx.x;
    if (i < NNODES) cnt[i] = 0;
    if (blockIdx.x == 0 && threadIdx.x < NBUCKET) gcur[threadIdx.x] = 0;
}

// Pass A: degree histogram + bucket partition (64 dest buckets, run-contiguous writes)
__global__ __launch_bounds__(256) void k_bucketA(const int* __restrict__ ei,
                                                 int* __restrict__ cnt,
                                                 int* __restrict__ gcur,
                                                 uintT* __restrict__ bucket){
    __shared__ int hist[NBUCKET];
    __shared__ int base[NBUCKET];
    int t = threadIdx.x;
    if (t < NBUCKET) hist[t] = 0;
    __syncthreads();
    int e0 = blockIdx.x * EPW;
    for (int i = t; i < EPW; i += 256){
        int c = ei[NEDGES + e0 + i];
        atomicAdd(&cnt[c], 1);
        atomicAdd(&hist[c / BSPAN], 1);
    }
    __syncthreads();
    if (t < NBUCKET){
        base[t] = atomicAdd(&gcur[t], hist[t]);
        hist[t] = 0;   // reuse as local cursor
    }
    __syncthreads();
    for (int i = t; i < EPW; i += 256){
        int r = ei[e0 + i];
        int c = ei[NEDGES + e0 + i];
        int b = c / BSPAN;
        int lp = atomicAdd(&hist[b], 1);
        bucket[(size_t)b*BCAP + base[b] + lp] = ((uintT)c << 16) | (uintT)r;
    }
}

__global__ __launch_bounds__(256) void k_blocksum(const int* __restrict__ cnt, int* __restrict__ bsum){
    __shared__ int sm[256];
    int t = threadIdx.x;
    int i = blockIdx.x*256 + t;
    sm[t] = (i < NNODES) ? cnt[i] : 0;
    __syncthreads();
    for (int off = 128; off > 0; off >>= 1){
        if (t < off) sm[t] += sm[t+off];
        __syncthreads();
    }
    if (t == 0) bsum[blockIdx.x] = sm[0];
}
__global__ __launch_bounds__(256) void k_scanblocks(int* __restrict__ bsum){
    __shared__ int sm[256];
    int t = threadIdx.x;
    int v = (t < NBLK_SCAN) ? bsum[t] : 0;
    sm[t] = v;
    __syncthreads();
    for (int off = 1; off < 256; off <<= 1){
        int tv = (t >= off) ? sm[t-off] : 0;
        __syncthreads();
        sm[t] += tv;
        __syncthreads();
    }
    if (t < NBLK_SCAN) bsum[t] = sm[t] - v;   // exclusive
}
__global__ __launch_bounds__(256) void k_scanfinal(const int* __restrict__ cnt,
                                                   const int* __restrict__ bsum,
                                                   int* __restrict__ offs,
                                                   float* __restrict__ dinv){
    __shared__ int sm[256];
    int t = threadIdx.x;
    int i = blockIdx.x*256 + t;
    int v = (i < NNODES) ? cnt[i] : 0;
    sm[t] = v;
    __syncthreads();
    for (int off = 1; off < 256; off <<= 1){
        int tv = (t >= off) ? sm[t-off] : 0;
        __syncthreads();
        sm[t] += tv;
        __syncthreads();
    }
    int excl = sm[t] - v + bsum[blockIdx.x];
    if (i < NNODES){
        offs[i] = excl;
        dinv[i] = rsqrtf((float)(v + 1));   // +1 self loop
    }
    if (i == 0) offs[NNODES] = NEDGES;
}

// Pass B: per-bucket scatter into contiguous csr2 window (LDS cursors, no device atomics)
__global__ __launch_bounds__(256) void k_bucketB(const int* __restrict__ offs,
                                                 const int* __restrict__ gcur,
                                                 const uintT* __restrict__ bucket,
                                                 ushortT* __restrict__ csr2){
    __shared__ int lcur[BSPAN];
    int b = blockIdx.x;
    int t = threadIdx.x;
    int n0 = b * BSPAN;
    int nn = min(BSPAN, NNODES - n0);
    for (int i = t; i < nn; i += 256) lcur[i] = offs[n0 + i];
    __syncthreads();
    int count = gcur[b];
    const uintT* src = bucket + (size_t)b*BCAP;
    for (int i = t; i < count; i += 256){
        uintT e = src[i];
        int c = e >> 16;
        int r = e & 0xFFFFu;
        int pos = atomicAdd(&lcur[c - n0], 1);
        csr2[pos] = (ushortT)r;
    }
}

// ---------------- GEMM body [nrows,128] x [128,128] ----------------
// OUTMODE 0: fp32 row-major out, +bias +gelu
// OUTMODE 1: bf16 chunk-transposed out, scaled by dinv[row]
template<int OUTMODE>
__device__ __forceinline__ void gemm128_body(const float* __restrict__ A,
                                             const float* __restrict__ W,
                                             const float* __restrict__ scale,
                                             const float* __restrict__ bias,
                                             const float* __restrict__ dinv,
                                             void* __restrict__ Yout, int bid){
    __shared__ float As[128*40];
    __shared__ float Ws[32*132];
    int t = threadIdx.x;
    int tx = t & 15;
    int ty = t >> 4;
    int row0 = bid * 128;

    float acc[8][8];
    #pragma unroll
    for (int a=0;a<8;a++)
        #pragma unroll
        for (int b=0;b<8;b++) acc[a][b]=0.f;

    for (int k0 = 0; k0 < 128; k0 += 32){
        #pragma unroll
        for (int p=0;p<4;p++){
            int l = p*256 + t;
            int r = l >> 3;
            int c4 = l & 7;
            int gr = row0 + r;
            float4 v = make_float4(0.f,0.f,0.f,0.f);
            if (gr < NNODES) v = *(const float4*)&A[(size_t)gr*FDIM + k0 + c4*4];
            if (scale){
                float4 s = *(const float4*)&scale[k0 + c4*4];
                v.x*=s.x; v.y*=s.y; v.z*=s.z; v.w*=s.w;
            }
            *(float4*)&As[r*40 + c4*4] = v;
        }
        #pragma unroll
        for (int p=0;p<4;p++){
            int l = p*256 + t;
            int kk = l >> 5;
            int j4 = l & 31;
            float4 v = *(const float4*)&W[(size_t)(k0+kk)*FDIM + j4*4];
            *(float4*)&Ws[kk*132 + j4*4] = v;
        }
        __syncthreads();
        #pragma unroll
        for (int kk = 0; kk < 32; kk += 4){
            float4 af[8];
            #pragma unroll
            for (int rr=0;rr<8;rr++){
                int r = ty + 16*rr;
                af[rr] = *(const float4*)&As[r*40 + kk];
            }
            #pragma unroll
            for (int kv=0;kv<4;kv++){
                const float4 w0 = *(const float4*)&Ws[(kk+kv)*132 + tx*4];
                const float4 w1 = *(const float4*)&Ws[(kk+kv)*132 + 64 + tx*4];
                #pragma unroll
                for (int rr=0;rr<8;rr++){
                    const float av = (kv==0) ? af[rr].x : (kv==1) ? af[rr].y :
                                     (kv==2) ? af[rr].z : af[rr].w;
                    acc[rr][0]=fmaf(av,w0.x,acc[rr][0]);
                    acc[rr][1]=fmaf(av,w0.y,acc[rr][1]);
                    acc[rr][2]=fmaf(av,w0.z,acc[rr][2]);
                    acc[rr][3]=fmaf(av,w0.w,acc[rr][3]);
                    acc[rr][4]=fmaf(av,w1.x,acc[rr][4]);
                    acc[rr][5]=fmaf(av,w1.y,acc[rr][5]);
                    acc[rr][6]=fmaf(av,w1.z,acc[rr][6]);
                    acc[rr][7]=fmaf(av,w1.w,acc[rr][7]);
                }
            }
        }
        __syncthreads();
    }
    float4 bv0 = make_float4(0.f,0.f,0.f,0.f), bv1 = bv0;
    if (OUTMODE == 0 && bias){
        bv0 = *(const float4*)&bias[tx*4];
        bv1 = *(const float4*)&bias[64 + tx*4];
    }
    #pragma unroll
    for (int rr=0;rr<8;rr++){
        int row = row0 + ty + 16*rr;
        if (row < NNODES){
            float4 v0, v1;
            v0.x=acc[rr][0]; v0.y=acc[rr][1]; v0.z=acc[rr][2]; v0.w=acc[rr][3];
            v1.x=acc[rr][4]; v1.y=acc[rr][5]; v1.z=acc[rr][6]; v1.w=acc[rr][7];
            if (OUTMODE == 1){
                float dv = dinv[row];
                v0.x*=dv; v0.y*=dv; v0.z*=dv; v0.w*=dv;
                v1.x*=dv; v1.y*=dv; v1.z*=dv; v1.w*=dv;
                ushortT* Yb = (ushortT*)Yout;
                ushort4 o0, o1;
                o0.x=f2bf(v0.x); o0.y=f2bf(v0.y); o0.z=f2bf(v0.z); o0.w=f2bf(v0.w);
                o1.x=f2bf(v1.x); o1.y=f2bf(v1.y); o1.z=f2bf(v1.z); o1.w=f2bf(v1.w);
                int jA = tx*4;           // 0..60 -> chunks 0,1
                int cA = jA >> 5, oA = jA & 31;
                int jB = 64 + tx*4;      // 64..124 -> chunks 2,3
                int cB = jB >> 5, oB = jB & 31;
                *(ushort4*)&Yb[((size_t)cA*NNODES + row)*32 + oA] = o0;
                *(ushort4*)&Yb[((size_t)cB*NNODES + row)*32 + oB] = o1;
            } else {
                v0.x=gelu_erf(v0.x+bv0.x); v0.y=gelu_erf(v0.y+bv0.y);
                v0.z=gelu_erf(v0.z+bv0.z); v0.w=gelu_erf(v0.w+bv0.w);
                v1.x=gelu_erf(v1.x+bv1.x); v1.y=gelu_erf(v1.y+bv1.y);
                v1.z=gelu_erf(v1.z+bv1.z); v1.w=gelu_erf(v1.w+bv1.w);
                float* Yf = (float*)Yout;
                *(float4*)&Yf[(size_t)row*FDIM + tx*4] = v0;
                *(float4*)&Yf[(size_t)row*FDIM + 64 + tx*4] = v1;
            }
        }
    }
}

__global__ __launch_bounds__(256) void k_gemm_t(const float* __restrict__ A,
                                                const float* __restrict__ W,
                                                const float* __restrict__ scale,
                                                const float* __restrict__ dinv,
                                                ushortT* __restrict__ Yt){
    gemm128_body<1>(A, W, scale, nullptr, dinv, (void*)Yt, blockIdx.x);
}
__global__ __launch_bounds__(256) void k_gemm_f(const float* __restrict__ A,
                                                const float* __restrict__ W,
                                                const float* __restrict__ bias,
                                                float* __restrict__ Y){
    gemm128_body<0>(A, W, nullptr, bias, nullptr, (void*)Y, blockIdx.x);
}

// ---------------- sharded aggregation ----------------
// chunk = blockIdx&3 (32 feats = one 64B line per node); 16 nodes/block, 16 lanes/node.
__global__ __launch_bounds__(256) void k_aggregate(const ushortT* __restrict__ Yt,
                                                   const float* __restrict__ dinv,
                                                   const int* __restrict__ offs,
                                                   const ushortT* __restrict__ csr2,
                                                   const float* __restrict__ bias,
                                                   float* __restrict__ Hout){
    int bid = blockIdx.x;
    int chunk = bid & 3;
    int node = (bid >> 2) * 16 + (threadIdx.x >> 4);
    int lane = threadIdx.x & 15;
    const uintT* Yc = (const uintT*)Yt + (size_t)chunk * NNODES * 16;

    uintT a0 = Yc[node*16 + lane];
    float2 acc;
    acc.x = bflo(a0);
    acc.y = bfhi(a0);
    int e0 = offs[node], e1 = offs[node+1];
    int e = e0;
    for (; e + 3 < e1; e += 4){
        int r0 = csr2[e+0];
        int r1 = csr2[e+1];
        int r2 = csr2[e+2];
        int r3 = csr2[e+3];
        uintT q0 = Yc[r0*16 + lane];
        uintT q1 = Yc[r1*16 + lane];
        uintT q2 = Yc[r2*16 + lane];
        uintT q3 = Yc[r3*16 + lane];
        acc.x += bflo(q0); acc.y += bfhi(q0);
        acc.x += bflo(q1); acc.y += bfhi(q1);
        acc.x += bflo(q2); acc.y += bfhi(q2);
        acc.x += bflo(q3); acc.y += bfhi(q3);
    }
    for (; e < e1; e++){
        int r = csr2[e];
        uintT q = Yc[r*16 + lane];
        acc.x += bflo(q); acc.y += bfhi(q);
    }
    float dc = dinv[node];
    float2 bv = ((const float2*)bias)[chunk*16 + lane];
    acc.x = gelu_erf(fmaf(dc, acc.x, bv.x));
    acc.y = gelu_erf(fmaf(dc, acc.y, bv.y));
    float* dst = &Hout[(size_t)node*FDIM + chunk*32 + lane*2];
    __builtin_nontemporal_store(acc.x, dst);
    __builtin_nontemporal_store(acc.y, dst+1);
}

// ---------------- final GEMM [nrows,128] x [128,16] + bias ----------------
__global__ __launch_bounds__(256) void k_gemm16(const float* __restrict__ A,
                                                const float* __restrict__ W,
                                                const float* __restrict__ bias,
                                                float* __restrict__ out){
    __shared__ float Hs[16][132];
    __shared__ float Ws2[128][16];
    int row0 = blockIdx.x * 16;
    int t = threadIdx.x;
    #pragma unroll
    for (int p=0;p<8;p++){
        int lin = p*256 + t;
        int r = lin >> 7, c = lin & 127;
        Hs[r][c] = A[(row0+r)*FDIM + c];
    }
    #pragma unroll
    for (int p=0;p<8;p++){
        int lin = p*256 + t;
        Ws2[lin>>4][lin&15] = W[lin];
    }
    __syncthreads();
    int il = t >> 4, j = t & 15;
    float acc = bias[j];
    #pragma unroll
    for (int k=0;k<FDIM;k++) acc = fmaf(Hs[il][k], Ws2[k][j], acc);
    out[(row0+il)*16 + j] = acc;
}

extern "C" void kernel_launch(void* const* d_in, const int* in_sizes, int n_in,
                              void* d_out, int out_size, void* d_ws, size_t ws_size,
                              hipStream_t stream) {
    const float* x    = (const float*)d_in[0];
    const int*   ei   = (const int*)d_in[1];
    const float* imp  = (const float*)d_in[2];
    const float* W1   = (const float*)d_in[3];
    const float* b1   = (const float*)d_in[4];
    const float* W2   = (const float*)d_in[5];
    const float* b2   = (const float*)d_in[6];
    const float* W3   = (const float*)d_in[7];
    const float* b3   = (const float*)d_in[8];
    const float* lw1  = (const float*)d_in[9];
    const float* lb1  = (const float*)d_in[10];
    const float* lw2  = (const float*)d_in[11];
    const float* lb2  = (const float*)d_in[12];
    float* out = (float*)d_out;

    // workspace layout (units of 4 bytes)
    int*   cnt    = (int*)d_ws;                          // 50000
    int*   offs   = (int*)d_ws + 50176;                  // 50001
    int*   bsum   = (int*)d_ws + 100480;                 // 256
    int*   gcur   = (int*)d_ws + 100736;                 // 64
    float* dinv   = (float*)d_ws + 100800;               // 50000
    ushortT* csr2 = (ushortT*)((int*)d_ws + 150800);     // 800000 ushort (1.6 MB)
    uintT* bucket = (uintT*)((int*)d_ws + 550912);       // 64*16384 uint (4 MB)
    ushortT* bufYt= (ushortT*)((int*)d_ws + 1599488);    // 50000*128 bf16 transposed (12.8 MB)
    float* bufY   = (float*)d_ws + 1599488;              // alias: fp32 lw1 output (used after Yt dead)
    float* bufH   = (float*)d_ws + 7999488;              // N*128 fp32 (25.6 MB)

    dim3 B(256);
    // ---- CSR build ----
    k_zero      <<<NBLK_SCAN, B, 0, stream>>>(cnt, gcur);
    k_bucketA   <<<ABLK, B, 0, stream>>>(ei, cnt, gcur, bucket);
    k_blocksum  <<<NBLK_SCAN, B, 0, stream>>>(cnt, bsum);
    k_scanblocks<<<1, B, 0, stream>>>(bsum);
    k_scanfinal <<<NBLK_SCAN, B, 0, stream>>>(cnt, bsum, offs, dinv);
    k_bucketB   <<<NBUCKET, B, 0, stream>>>(offs, gcur, bucket, csr2);

    // ---- conv layers ----
    k_gemm_t   <<<GGRID, B, 0, stream>>>(x, W1, imp, dinv, bufYt);
    k_aggregate<<<(NNODES/16)*4, B, 0, stream>>>(bufYt, dinv, offs, csr2, b1, bufH);
    k_gemm_t   <<<GGRID, B, 0, stream>>>(bufH, W2, nullptr, dinv, bufYt);
    k_aggregate<<<(NNODES/16)*4, B, 0, stream>>>(bufYt, dinv, offs, csr2, b2, bufH);
    k_gemm_t   <<<GGRID, B, 0, stream>>>(bufH, W3, nullptr, dinv, bufYt);
    k_aggregate<<<(NNODES/16)*4, B, 0, stream>>>(bufYt, dinv, offs, csr2, b3, bufH);

    // ---- h = gelu(h @ lw1 + lb1) ----
    k_gemm_f<<<GGRID, B, 0, stream>>>(bufH, lw1, lb1, bufY);
    // ---- out = h @ lw2 + lb2 ----
    k_gemm16<<<NNODES/16, B, 0, stream>>>(bufY, lw2, lb2, out);
}

// Round 7
// 376.010 us; speedup vs baseline: 1.1453x; 1.1270x over previous
//
#include <hip/hip_runtime.h>
#include <math.h>

#define NNODES 50000
#define NEDGES 800000
#define FDIM 128
#define GGRID 391       // ceil(50000/128)
#define NBUCKET 196     // buckets of 256 nodes: 196*256 = 50176 >= 50000
#define BCAP 6144       // capacity per bucket (mean 4082, +32 sigma)
#define ABLK 261        // pass-A workgroups
#define EPWA 3072       // edges per pass-A wg (261*3072 >= 800000)

typedef unsigned short ushortT;
typedef unsigned int uintT;

__device__ __forceinline__ float gelu_erf(float x){
    return 0.5f * x * (1.0f + erff(x * 0.70710678118654752f));
}
// bf16 helpers: packed ushort2 in a uint
__device__ __forceinline__ float bflo(uintT u){ return __uint_as_float(u << 16); }
__device__ __forceinline__ float bfhi(uintT u){ return __uint_as_float(u & 0xFFFF0000u); }
__device__ __forceinline__ ushortT f2bf(float f){
    uintT u = __float_as_uint(f);
    return (ushortT)((u + 0x7FFFu + ((u >> 16) & 1u)) >> 16);   // RNE
}

// ---------------- CSR build ----------------
__global__ void k_zero(int* __restrict__ gcur){
    if (threadIdx.x < NBUCKET) gcur[threadIdx.x] = 0;
}

// Pass A: partition edges into 196 buckets by c>>8; packed (c<<16|r); run-contiguous writes.
__global__ __launch_bounds__(256) void k_bucketA(const int* __restrict__ ei,
                                                 int* __restrict__ gcur,
                                                 uintT* __restrict__ bucket){
    __shared__ int hist[NBUCKET];
    __shared__ int base[NBUCKET];
    int t = threadIdx.x;
    if (t < NBUCKET) hist[t] = 0;
    __syncthreads();
    int e0 = blockIdx.x * EPWA;
    int cr_c[12], cr_r[12];
    #pragma unroll
    for (int p = 0; p < 12; p++){
        int e = e0 + p*256 + t;
        if (e < NEDGES){
            cr_r[p] = ei[e];
            cr_c[p] = ei[NEDGES + e];
            atomicAdd(&hist[cr_c[p] >> 8], 1);
        } else cr_c[p] = -1;
    }
    __syncthreads();
    if (t < NBUCKET){
        base[t] = atomicAdd(&gcur[t], hist[t]);
        hist[t] = 0;   // reuse as local cursor
    }
    __syncthreads();
    #pragma unroll
    for (int p = 0; p < 12; p++){
        int c = cr_c[p];
        if (c >= 0){
            int b = c >> 8;
            int lp = atomicAdd(&hist[b], 1);
            bucket[(size_t)b*BCAP + base[b] + lp] = ((uintT)c << 16) | (uintT)cr_r[p];
        }
    }
}

// Pass B: per-bucket (256 nodes) — degree hist + offs/dinv via LDS scan + ordered scatter.
__global__ __launch_bounds__(256) void k_bucketB(const int* __restrict__ gcur,
                                                 const uintT* __restrict__ bucket,
                                                 int* __restrict__ offs,
                                                 float* __restrict__ dinv,
                                                 ushortT* __restrict__ csr2){
    __shared__ int sm[256];
    __shared__ int hist[256];
    __shared__ int lcur[256];
    int b = blockIdx.x;
    int t = threadIdx.x;
    int n0 = b << 8;

    // exclusive scan of gcur[0..195] -> bucket base
    int gv = (t < NBUCKET) ? gcur[t] : 0;
    sm[t] = gv;
    __syncthreads();
    for (int off = 1; off < 256; off <<= 1){
        int tv = (t >= off) ? sm[t-off] : 0;
        __syncthreads();
        sm[t] += tv;
        __syncthreads();
    }
    __shared__ int bbase_s;
    if (t == b) bbase_s = sm[t] - gv;
    hist[t] = 0;
    __syncthreads();
    int bbase = bbase_s;
    int count = gcur[b];
    const uintT* src = bucket + (size_t)b*BCAP;

    // phase 1: degree histogram within bucket
    for (int i = t; i < count; i += 256)
        atomicAdd(&hist[(src[i] >> 16) & 255], 1);
    __syncthreads();

    // phase 2: exclusive scan of hist -> offs, dinv, cursors
    int v = hist[t];
    sm[t] = v;
    __syncthreads();
    for (int off = 1; off < 256; off <<= 1){
        int tv = (t >= off) ? sm[t-off] : 0;
        __syncthreads();
        sm[t] += tv;
        __syncthreads();
    }
    int excl = bbase + sm[t] - v;
    int node = n0 + t;
    if (node <= NNODES) offs[node] = excl;
    if (node < NNODES) dinv[node] = rsqrtf((float)(v + 1));
    if (b == NBUCKET-1 && t == 255) offs[NNODES] = NEDGES;
    lcur[t] = excl;
    __syncthreads();

    // phase 3: scatter into contiguous csr2 window
    for (int i = t; i < count; i += 256){
        uintT e = src[i];
        int pos = atomicAdd(&lcur[(e >> 16) & 255], 1);
        csr2[pos] = (ushortT)(e & 0xFFFFu);
    }
}

// ---------------- GEMM body [nrows,128] x [128,128] ----------------
// OUTMODE 0: fp32 row-major out, +bias +gelu
// OUTMODE 1: bf16 chunk-transposed out, scaled by dinv[row]
template<int OUTMODE>
__device__ __forceinline__ void gemm128_body(const float* __restrict__ A,
                                             const float* __restrict__ W,
                                             const float* __restrict__ scale,
                                             const float* __restrict__ bias,
                                             const float* __restrict__ dinv,
                                             void* __restrict__ Yout, int bid){
    __shared__ float As[128*40];
    __shared__ float Ws[32*132];
    int t = threadIdx.x;
    int tx = t & 15;
    int ty = t >> 4;
    int row0 = bid * 128;

    float acc[8][8];
    #pragma unroll
    for (int a=0;a<8;a++)
        #pragma unroll
        for (int b=0;b<8;b++) acc[a][b]=0.f;

    for (int k0 = 0; k0 < 128; k0 += 32){
        #pragma unroll
        for (int p=0;p<4;p++){
            int l = p*256 + t;
            int r = l >> 3;
            int c4 = l & 7;
            int gr = row0 + r;
            float4 v = make_float4(0.f,0.f,0.f,0.f);
            if (gr < NNODES) v = *(const float4*)&A[(size_t)gr*FDIM + k0 + c4*4];
            if (scale){
                float4 s = *(const float4*)&scale[k0 + c4*4];
                v.x*=s.x; v.y*=s.y; v.z*=s.z; v.w*=s.w;
            }
            *(float4*)&As[r*40 + c4*4] = v;
        }
        #pragma unroll
        for (int p=0;p<4;p++){
            int l = p*256 + t;
            int kk = l >> 5;
            int j4 = l & 31;
            float4 v = *(const float4*)&W[(size_t)(k0+kk)*FDIM + j4*4];
            *(float4*)&Ws[kk*132 + j4*4] = v;
        }
        __syncthreads();
        #pragma unroll
        for (int kk = 0; kk < 32; kk += 4){
            float4 af[8];
            #pragma unroll
            for (int rr=0;rr<8;rr++){
                int r = ty + 16*rr;
                af[rr] = *(const float4*)&As[r*40 + kk];
            }
            #pragma unroll
            for (int kv=0;kv<4;kv++){
                const float4 w0 = *(const float4*)&Ws[(kk+kv)*132 + tx*4];
                const float4 w1 = *(const float4*)&Ws[(kk+kv)*132 + 64 + tx*4];
                #pragma unroll
                for (int rr=0;rr<8;rr++){
                    const float av = (kv==0) ? af[rr].x : (kv==1) ? af[rr].y :
                                     (kv==2) ? af[rr].z : af[rr].w;
                    acc[rr][0]=fmaf(av,w0.x,acc[rr][0]);
                    acc[rr][1]=fmaf(av,w0.y,acc[rr][1]);
                    acc[rr][2]=fmaf(av,w0.z,acc[rr][2]);
                    acc[rr][3]=fmaf(av,w0.w,acc[rr][3]);
                    acc[rr][4]=fmaf(av,w1.x,acc[rr][4]);
                    acc[rr][5]=fmaf(av,w1.y,acc[rr][5]);
                    acc[rr][6]=fmaf(av,w1.z,acc[rr][6]);
                    acc[rr][7]=fmaf(av,w1.w,acc[rr][7]);
                }
            }
        }
        __syncthreads();
    }
    float4 bv0 = make_float4(0.f,0.f,0.f,0.f), bv1 = bv0;
    if (OUTMODE == 0 && bias){
        bv0 = *(const float4*)&bias[tx*4];
        bv1 = *(const float4*)&bias[64 + tx*4];
    }
    #pragma unroll
    for (int rr=0;rr<8;rr++){
        int row = row0 + ty + 16*rr;
        if (row < NNODES){
            float4 v0, v1;
            v0.x=acc[rr][0]; v0.y=acc[rr][1]; v0.z=acc[rr][2]; v0.w=acc[rr][3];
            v1.x=acc[rr][4]; v1.y=acc[rr][5]; v1.z=acc[rr][6]; v1.w=acc[rr][7];
            if (OUTMODE == 1){
                float dv = dinv[row];
                v0.x*=dv; v0.y*=dv; v0.z*=dv; v0.w*=dv;
                v1.x*=dv; v1.y*=dv; v1.z*=dv; v1.w*=dv;
                ushortT* Yb = (ushortT*)Yout;
                ushort4 o0, o1;
                o0.x=f2bf(v0.x); o0.y=f2bf(v0.y); o0.z=f2bf(v0.z); o0.w=f2bf(v0.w);
                o1.x=f2bf(v1.x); o1.y=f2bf(v1.y); o1.z=f2bf(v1.z); o1.w=f2bf(v1.w);
                int jA = tx*4;           // 0..60 -> chunks 0,1
                int cA = jA >> 5, oA = jA & 31;
                int jB = 64 + tx*4;      // 64..124 -> chunks 2,3
                int cB = jB >> 5, oB = jB & 31;
                *(ushort4*)&Yb[((size_t)cA*NNODES + row)*32 + oA] = o0;
                *(ushort4*)&Yb[((size_t)cB*NNODES + row)*32 + oB] = o1;
            } else {
                v0.x=gelu_erf(v0.x+bv0.x); v0.y=gelu_erf(v0.y+bv0.y);
                v0.z=gelu_erf(v0.z+bv0.z); v0.w=gelu_erf(v0.w+bv0.w);
                v1.x=gelu_erf(v1.x+bv1.x); v1.y=gelu_erf(v1.y+bv1.y);
                v1.z=gelu_erf(v1.z+bv1.z); v1.w=gelu_erf(v1.w+bv1.w);
                float* Yf = (float*)Yout;
                *(float4*)&Yf[(size_t)row*FDIM + tx*4] = v0;
                *(float4*)&Yf[(size_t)row*FDIM + 64 + tx*4] = v1;
            }
        }
    }
}

__global__ __launch_bounds__(256) void k_gemm_t(const float* __restrict__ A,
                                                const float* __restrict__ W,
                                                const float* __restrict__ scale,
                                                const float* __restrict__ dinv,
                                                ushortT* __restrict__ Yt){
    gemm128_body<1>(A, W, scale, nullptr, dinv, (void*)Yt, blockIdx.x);
}
__global__ __launch_bounds__(256) void k_gemm_f(const float* __restrict__ A,
                                                const float* __restrict__ W,
                                                const float* __restrict__ bias,
                                                float* __restrict__ Y){
    gemm128_body<0>(A, W, nullptr, bias, nullptr, (void*)Y, blockIdx.x);
}

// ---------------- sharded aggregation ----------------
// chunk = blockIdx&3 (32 feats = one 64B line per node); 16 nodes/block, 16 lanes/node.
__global__ __launch_bounds__(256) void k_aggregate(const ushortT* __restrict__ Yt,
                                                   const float* __restrict__ dinv,
                                                   const int* __restrict__ offs,
                                                   const ushortT* __restrict__ csr2,
                                                   const float* __restrict__ bias,
                                                   float* __restrict__ Hout){
    int bid = blockIdx.x;
    int chunk = bid & 3;
    int node = (bid >> 2) * 16 + (threadIdx.x >> 4);
    int lane = threadIdx.x & 15;
    const uintT* Yc = (const uintT*)Yt + (size_t)chunk * NNODES * 16;

    uintT a0 = Yc[node*16 + lane];
    float2 acc;
    acc.x = bflo(a0);
    acc.y = bfhi(a0);
    int e0 = offs[node], e1 = offs[node+1];
    int e = e0;
    for (; e + 3 < e1; e += 4){
        int r0 = csr2[e+0];
        int r1 = csr2[e+1];
        int r2 = csr2[e+2];
        int r3 = csr2[e+3];
        uintT q0 = Yc[r0*16 + lane];
        uintT q1 = Yc[r1*16 + lane];
        uintT q2 = Yc[r2*16 + lane];
        uintT q3 = Yc[r3*16 + lane];
        acc.x += bflo(q0); acc.y += bfhi(q0);
        acc.x += bflo(q1); acc.y += bfhi(q1);
        acc.x += bflo(q2); acc.y += bfhi(q2);
        acc.x += bflo(q3); acc.y += bfhi(q3);
    }
    for (; e < e1; e++){
        int r = csr2[e];
        uintT q = Yc[r*16 + lane];
        acc.x += bflo(q); acc.y += bfhi(q);
    }
    float dc = dinv[node];
    float2 bv = ((const float2*)bias)[chunk*16 + lane];
    acc.x = gelu_erf(fmaf(dc, acc.x, bv.x));
    acc.y = gelu_erf(fmaf(dc, acc.y, bv.y));
    float* dst = &Hout[(size_t)node*FDIM + chunk*32 + lane*2];
    __builtin_nontemporal_store(acc.x, dst);
    __builtin_nontemporal_store(acc.y, dst+1);
}

// ---------------- final GEMM [nrows,128] x [128,16] + bias ----------------
__global__ __launch_bounds__(256) void k_gemm16(const float* __restrict__ A,
                                                const float* __restrict__ W,
                                                const float* __restrict__ bias,
                                                float* __restrict__ out){
    __shared__ float Hs[16][132];
    __shared__ float Ws2[128][16];
    int row0 = blockIdx.x * 16;
    int t = threadIdx.x;
    #pragma unroll
    for (int p=0;p<8;p++){
        int lin = p*256 + t;
        int r = lin >> 7, c = lin & 127;
        Hs[r][c] = A[(row0+r)*FDIM + c];
    }
    #pragma unroll
    for (int p=0;p<8;p++){
        int lin = p*256 + t;
        Ws2[lin>>4][lin&15] = W[lin];
    }
    __syncthreads();
    int il = t >> 4, j = t & 15;
    float acc = bias[j];
    #pragma unroll
    for (int k=0;k<FDIM;k++) acc = fmaf(Hs[il][k], Ws2[k][j], acc);
    out[(row0+il)*16 + j] = acc;
}

extern "C" void kernel_launch(void* const* d_in, const int* in_sizes, int n_in,
                              void* d_out, int out_size, void* d_ws, size_t ws_size,
                              hipStream_t stream) {
    const float* x    = (const float*)d_in[0];
    const int*   ei   = (const int*)d_in[1];
    const float* imp  = (const float*)d_in[2];
    const float* W1   = (const float*)d_in[3];
    const float* b1   = (const float*)d_in[4];
    const float* W2   = (const float*)d_in[5];
    const float* b2   = (const float*)d_in[6];
    const float* W3   = (const float*)d_in[7];
    const float* b3   = (const float*)d_in[8];
    const float* lw1  = (const float*)d_in[9];
    const float* lb1  = (const float*)d_in[10];
    const float* lw2  = (const float*)d_in[11];
    const float* lb2  = (const float*)d_in[12];
    float* out = (float*)d_out;

    // workspace layout (units of 4 bytes)
    int*   offs   = (int*)d_ws;                          // 50001
    int*   gcur   = (int*)d_ws + 50048;                  // 196
    float* dinv   = (float*)d_ws + 50304;                // 50000
    ushortT* csr2 = (ushortT*)((int*)d_ws + 100352);     // 800000 ushort (1.6 MB)
    uintT* bucket = (uintT*)((int*)d_ws + 500352);       // 196*6144 uint (4.8 MB)
    ushortT* bufYt= (ushortT*)((int*)d_ws + 1704576);    // 50000*128 bf16 transposed (12.8 MB)
    float* bufY   = (float*)d_ws + 1704576;              // alias: fp32 lw1 output (used after Yt dead)
    float* bufH   = (float*)d_ws + 8104576;              // N*128 fp32 (25.6 MB)

    dim3 B(256);
    // ---- CSR build ----
    k_zero   <<<1, B, 0, stream>>>(gcur);
    k_bucketA<<<ABLK, B, 0, stream>>>(ei, gcur, bucket);
    k_bucketB<<<NBUCKET, B, 0, stream>>>(gcur, bucket, offs, dinv, csr2);

    // ---- conv layers ----
    k_gemm_t   <<<GGRID, B, 0, stream>>>(x, W1, imp, dinv, bufYt);
    k_aggregate<<<(NNODES/16)*4, B, 0, stream>>>(bufYt, dinv, offs, csr2, b1, bufH);
    k_gemm_t   <<<GGRID, B, 0, stream>>>(bufH, W2, nullptr, dinv, bufYt);
    k_aggregate<<<(NNODES/16)*4, B, 0, stream>>>(bufYt, dinv, offs, csr2, b2, bufH);
    k_gemm_t   <<<GGRID, B, 0, stream>>>(bufH, W3, nullptr, dinv, bufYt);
    k_aggregate<<<(NNODES/16)*4, B, 0, stream>>>(bufYt, dinv, offs, csr2, b3, bufH);

    // ---- h = gelu(h @ lw1 + lb1) ----
    k_gemm_f<<<GGRID, B, 0, stream>>>(bufH, lw1, lb1, bufY);
    // ---- out = h @ lw2 + lb2 ----
    k_gemm16<<<NNODES/16, B, 0, stream>>>(bufY, lw2, lb2, out);
}

// Round 8
// 360.667 us; speedup vs baseline: 1.1940x; 1.0425x over previous
//
#include <hip/hip_runtime.h>
#include <math.h>

#define NNODES 50000
#define NEDGES 800000
#define FDIM 128
#define NBUCKET 196     // buckets of 256 nodes: 196*256 = 50176 >= 50000
#define BCAP 6144       // capacity per bucket (mean 4082, +32 sigma)
#define ABLK 261        // pass-A workgroups
#define EPWA 3072       // edges per pass-A wg (261*3072 >= 800000)
#define MGRID 782       // ceil(50000/64) MFMA-GEMM blocks

typedef unsigned short ushortT;
typedef unsigned int uintT;
typedef __attribute__((ext_vector_type(8))) short short8;
typedef __attribute__((ext_vector_type(4))) float floatx4;

__device__ __forceinline__ float gelu_erf(float x){
    return 0.5f * x * (1.0f + erff(x * 0.70710678118654752f));
}
// bf16 helpers
__device__ __forceinline__ float bflo(uintT u){ return __uint_as_float(u << 16); }
__device__ __forceinline__ float bfhi(uintT u){ return __uint_as_float(u & 0xFFFF0000u); }
__device__ __forceinline__ ushortT f2bf(float f){
    uintT u = __float_as_uint(f);
    return (ushortT)((u + 0x7FFFu + ((u >> 16) & 1u)) >> 16);   // RNE
}
// truncation split: f = hi + lo_resid; both bf16 (trunc). Residual error ~2^-16 rel.
__device__ __forceinline__ void split_bf16(float f, ushortT& hi, ushortT& lo){
    uintT u = __float_as_uint(f);
    hi = (ushortT)(u >> 16);
    float fhi = __uint_as_float(u & 0xFFFF0000u);
    lo = (ushortT)(__float_as_uint(f - fhi) >> 16);
}

// ---------------- CSR build ----------------
__global__ void k_zero(int* __restrict__ gcur){
    if (threadIdx.x < NBUCKET) gcur[threadIdx.x] = 0;
}

__global__ __launch_bounds__(256) void k_bucketA(const int* __restrict__ ei,
                                                 int* __restrict__ gcur,
                                                 uintT* __restrict__ bucket){
    __shared__ int hist[NBUCKET];
    __shared__ int base[NBUCKET];
    int t = threadIdx.x;
    if (t < NBUCKET) hist[t] = 0;
    __syncthreads();
    int e0 = blockIdx.x * EPWA;
    int cr_c[12], cr_r[12];
    #pragma unroll
    for (int p = 0; p < 12; p++){
        int e = e0 + p*256 + t;
        if (e < NEDGES){
            cr_r[p] = ei[e];
            cr_c[p] = ei[NEDGES + e];
            atomicAdd(&hist[cr_c[p] >> 8], 1);
        } else cr_c[p] = -1;
    }
    __syncthreads();
    if (t < NBUCKET){
        base[t] = atomicAdd(&gcur[t], hist[t]);
        hist[t] = 0;   // reuse as local cursor
    }
    __syncthreads();
    #pragma unroll
    for (int p = 0; p < 12; p++){
        int c = cr_c[p];
        if (c >= 0){
            int b = c >> 8;
            int lp = atomicAdd(&hist[b], 1);
            bucket[(size_t)b*BCAP + base[b] + lp] = ((uintT)c << 16) | (uintT)cr_r[p];
        }
    }
}

__global__ __launch_bounds__(256) void k_bucketB(const int* __restrict__ gcur,
                                                 const uintT* __restrict__ bucket,
                                                 int* __restrict__ offs,
                                                 float* __restrict__ dinv,
                                                 ushortT* __restrict__ csr2){
    __shared__ int sm[256];
    __shared__ int hist[256];
    __shared__ int lcur[256];
    int b = blockIdx.x;
    int t = threadIdx.x;
    int n0 = b << 8;

    int gv = (t < NBUCKET) ? gcur[t] : 0;
    sm[t] = gv;
    __syncthreads();
    for (int off = 1; off < 256; off <<= 1){
        int tv = (t >= off) ? sm[t-off] : 0;
        __syncthreads();
        sm[t] += tv;
        __syncthreads();
    }
    __shared__ int bbase_s;
    if (t == b) bbase_s = sm[t] - gv;
    hist[t] = 0;
    __syncthreads();
    int bbase = bbase_s;
    int count = gcur[b];
    const uintT* src = bucket + (size_t)b*BCAP;

    for (int i = t; i < count; i += 256)
        atomicAdd(&hist[(src[i] >> 16) & 255], 1);
    __syncthreads();

    int v = hist[t];
    sm[t] = v;
    __syncthreads();
    for (int off = 1; off < 256; off <<= 1){
        int tv = (t >= off) ? sm[t-off] : 0;
        __syncthreads();
        sm[t] += tv;
        __syncthreads();
    }
    int excl = bbase + sm[t] - v;
    int node = n0 + t;
    if (node <= NNODES) offs[node] = excl;
    if (node < NNODES) dinv[node] = rsqrtf((float)(v + 1));
    if (b == NBUCKET-1 && t == 255) offs[NNODES] = NEDGES;
    lcur[t] = excl;
    __syncthreads();

    for (int i = t; i < count; i += 256){
        uintT e = src[i];
        int pos = atomicAdd(&lcur[(e >> 16) & 255], 1);
        csr2[pos] = (ushortT)(e & 0xFFFFu);
    }
}

// ---------------- weight prepack: fp32 [128][128] -> bf16 hi/lo planes in B-frag order ----
// B-frag for mfma_f32_16x16x32_bf16: lane holds B[k=quad*8+j][n=(lane&15)+nt*16], j=0..7.
// Packed offset: ((kc*8+nt)*64 + lane)*8 + j     (kc = k>>5, quad = (k>>3)&3)
__global__ __launch_bounds__(256) void k_packW(const float* __restrict__ Wa,
                                               const float* __restrict__ Wb,
                                               const float* __restrict__ Wc,
                                               const float* __restrict__ Wd,
                                               ushortT* __restrict__ Wp){
    int l = blockIdx.x;
    const float* W = (l==0) ? Wa : (l==1) ? Wb : (l==2) ? Wc : Wd;
    ushortT* hiP = Wp + (size_t)l*2*16384;
    ushortT* loP = hiP + 16384;
    for (int idx = threadIdx.x; idx < 16384; idx += 256){
        int k = idx >> 7, n = idx & 127;
        ushortT hi, lo;
        split_bf16(W[idx], hi, lo);
        int kc = k >> 5, quad = (k >> 3) & 3, j = k & 7;
        int nt = n >> 4, lane = (n & 15) + (quad << 4);
        int off = ((kc*8 + nt)*64 + lane)*8 + j;
        hiP[off] = hi;
        loP[off] = lo;
    }
}

// ---------------- MFMA GEMM [nrows,128] x [128,128], split-bf16 (bf16x3) -------------
// 64 rows/block (4 waves x 16). Zero LDS: A-frags from global fp32 (split in-reg),
// B-frags from prepacked planes. A-frag: row=lane&15, k=quad*8+j. D: col=lane&15,
// row=quad*4+reg.
// OUTMODE 1: Y bf16 chunk-transposed, scaled by dinv[row].  OUTMODE 0: fp32 +bias +gelu.
template<int OUTMODE>
__global__ __launch_bounds__(256) void k_mfma(const float* __restrict__ A,
                                              const ushortT* __restrict__ Wp,
                                              const float* __restrict__ scale,
                                              const float* __restrict__ dinv,
                                              const float* __restrict__ bias,
                                              void* __restrict__ Yout){
    int t = threadIdx.x;
    int wave = t >> 6, lane = t & 63;
    int r = lane & 15, quad = lane >> 4;
    int m0 = blockIdx.x*64 + wave*16;
    int arow = m0 + r;
    if (arow >= NNODES) arow = NNODES - 1;
    const ushortT* WpLo = Wp + 16384;

    floatx4 acc[8];
    #pragma unroll
    for (int nt = 0; nt < 8; nt++) acc[nt] = (floatx4){0.f,0.f,0.f,0.f};

    #pragma unroll
    for (int kc = 0; kc < 4; kc++){
        int kb = kc*32 + quad*8;
        float4 a0 = *(const float4*)&A[(size_t)arow*FDIM + kb];
        float4 a1 = *(const float4*)&A[(size_t)arow*FDIM + kb + 4];
        if (scale){
            float4 s0 = *(const float4*)&scale[kb];
            float4 s1 = *(const float4*)&scale[kb + 4];
            a0.x*=s0.x; a0.y*=s0.y; a0.z*=s0.z; a0.w*=s0.w;
            a1.x*=s1.x; a1.y*=s1.y; a1.z*=s1.z; a1.w*=s1.w;
        }
        float av[8] = {a0.x, a0.y, a0.z, a0.w, a1.x, a1.y, a1.z, a1.w};
        short8 ahi, alo;
        #pragma unroll
        for (int e = 0; e < 8; e++){
            ushortT h, l;
            split_bf16(av[e], h, l);
            ahi[e] = (short)h;
            alo[e] = (short)l;
        }
        #pragma unroll
        for (int nt = 0; nt < 8; nt++){
            size_t boff = (size_t)(((kc*8 + nt)*64 + lane))*8;
            short8 bhi = *(const short8*)&Wp[boff];
            short8 blo = *(const short8*)&WpLo[boff];
            acc[nt] = __builtin_amdgcn_mfma_f32_16x16x32_bf16(ahi, bhi, acc[nt], 0, 0, 0);
            acc[nt] = __builtin_amdgcn_mfma_f32_16x16x32_bf16(alo, bhi, acc[nt], 0, 0, 0);
            acc[nt] = __builtin_amdgcn_mfma_f32_16x16x32_bf16(ahi, blo, acc[nt], 0, 0, 0);
        }
    }

    int orow0 = m0 + quad*4;
    if (OUTMODE == 1){
        float4 dv = *(const float4*)&dinv[orow0];
        float dva[4] = {dv.x, dv.y, dv.z, dv.w};
        ushortT* Yb = (ushortT*)Yout;
        #pragma unroll
        for (int nt = 0; nt < 8; nt++){
            int n = nt*16 + r;
            int chunk = n >> 5, o = n & 31;
            #pragma unroll
            for (int reg = 0; reg < 4; reg++){
                int orow = orow0 + reg;
                if (orow < NNODES){
                    float v = acc[nt][reg] * dva[reg];
                    Yb[((size_t)chunk*NNODES + orow)*32 + o] = f2bf(v);
                }
            }
        }
    } else {
        float* Yf = (float*)Yout;
        #pragma unroll
        for (int nt = 0; nt < 8; nt++){
            int n = nt*16 + r;
            float bv = bias[n];
            #pragma unroll
            for (int reg = 0; reg < 4; reg++){
                int orow = orow0 + reg;
                if (orow < NNODES){
                    Yf[(size_t)orow*FDIM + n] = gelu_erf(acc[nt][reg] + bv);
                }
            }
        }
    }
}

// ---------------- sharded aggregation ----------------
__global__ __launch_bounds__(256) void k_aggregate(const ushortT* __restrict__ Yt,
                                                   const float* __restrict__ dinv,
                                                   const int* __restrict__ offs,
                                                   const ushortT* __restrict__ csr2,
                                                   const float* __restrict__ bias,
                                                   float* __restrict__ Hout){
    int bid = blockIdx.x;
    int chunk = bid & 3;
    int node = (bid >> 2) * 16 + (threadIdx.x >> 4);
    int lane = threadIdx.x & 15;
    const uintT* Yc = (const uintT*)Yt + (size_t)chunk * NNODES * 16;

    uintT a0 = Yc[node*16 + lane];
    float2 acc;
    acc.x = bflo(a0);
    acc.y = bfhi(a0);
    int e0 = offs[node], e1 = offs[node+1];
    int e = e0;
    for (; e + 3 < e1; e += 4){
        int r0 = csr2[e+0];
        int r1 = csr2[e+1];
        int r2 = csr2[e+2];
        int r3 = csr2[e+3];
        uintT q0 = Yc[r0*16 + lane];
        uintT q1 = Yc[r1*16 + lane];
        uintT q2 = Yc[r2*16 + lane];
        uintT q3 = Yc[r3*16 + lane];
        acc.x += bflo(q0); acc.y += bfhi(q0);
        acc.x += bflo(q1); acc.y += bfhi(q1);
        acc.x += bflo(q2); acc.y += bfhi(q2);
        acc.x += bflo(q3); acc.y += bfhi(q3);
    }
    for (; e < e1; e++){
        int r = csr2[e];
        uintT q = Yc[r*16 + lane];
        acc.x += bflo(q); acc.y += bfhi(q);
    }
    float dc = dinv[node];
    float2 bv = ((const float2*)bias)[chunk*16 + lane];
    acc.x = gelu_erf(fmaf(dc, acc.x, bv.x));
    acc.y = gelu_erf(fmaf(dc, acc.y, bv.y));
    float* dst = &Hout[(size_t)node*FDIM + chunk*32 + lane*2];
    __builtin_nontemporal_store(acc.x, dst);
    __builtin_nontemporal_store(acc.y, dst+1);
}

// ---------------- final GEMM [nrows,128] x [128,16] + bias ----------------
__global__ __launch_bounds__(256) void k_gemm16(const float* __restrict__ A,
                                                const float* __restrict__ W,
                                                const float* __restrict__ bias,
                                                float* __restrict__ out){
    __shared__ float Hs[16][132];
    __shared__ float Ws2[128][16];
    int row0 = blockIdx.x * 16;
    int t = threadIdx.x;
    #pragma unroll
    for (int p=0;p<8;p++){
        int lin = p*256 + t;
        int r = lin >> 7, c = lin & 127;
        Hs[r][c] = A[(row0+r)*FDIM + c];
    }
    #pragma unroll
    for (int p=0;p<8;p++){
        int lin = p*256 + t;
        Ws2[lin>>4][lin&15] = W[lin];
    }
    __syncthreads();
    int il = t >> 4, j = t & 15;
    float acc = bias[j];
    #pragma unroll
    for (int k=0;k<FDIM;k++) acc = fmaf(Hs[il][k], Ws2[k][j], acc);
    out[(row0+il)*16 + j] = acc;
}

extern "C" void kernel_launch(void* const* d_in, const int* in_sizes, int n_in,
                              void* d_out, int out_size, void* d_ws, size_t ws_size,
                              hipStream_t stream) {
    const float* x    = (const float*)d_in[0];
    const int*   ei   = (const int*)d_in[1];
    const float* imp  = (const float*)d_in[2];
    const float* W1   = (const float*)d_in[3];
    const float* b1   = (const float*)d_in[4];
    const float* W2   = (const float*)d_in[5];
    const float* b2   = (const float*)d_in[6];
    const float* W3   = (const float*)d_in[7];
    const float* b3   = (const float*)d_in[8];
    const float* lw1  = (const float*)d_in[9];
    const float* lb1  = (const float*)d_in[10];
    const float* lw2  = (const float*)d_in[11];
    const float* lb2  = (const float*)d_in[12];
    float* out = (float*)d_out;

    // workspace layout (units of 4 bytes)
    int*   offs   = (int*)d_ws;                          // 50001 (pad to 50048)
    int*   gcur   = (int*)d_ws + 50048;                  // 196 (pad to 256)
    float* dinv   = (float*)d_ws + 50304;                // 50000 (+pad; reads up to 50047 OK)
    ushortT* csr2 = (ushortT*)((int*)d_ws + 100480);     // 800000 ushort (1.6 MB)
    uintT* bucket = (uintT*)((int*)d_ws + 500480);       // 196*6144 uint (4.8 MB)
    ushortT* Wp   = (ushortT*)((int*)d_ws + 1704704);    // 4 layers * 2 planes * 16384 ushort (256 KB)
    ushortT* bufYt= (ushortT*)((int*)d_ws + 1770240);    // 50000*128 bf16 transposed (12.8 MB)
    float* bufY   = (float*)d_ws + 1770240;              // alias: fp32 lw1 output (used after Yt dead)
    float* bufH   = (float*)d_ws + 8170240;              // N*128 fp32 (25.6 MB)

    dim3 B(256);
    // ---- weight prepack + CSR build ----
    k_packW  <<<4, B, 0, stream>>>(W1, W2, W3, lw1, Wp);
    k_zero   <<<1, B, 0, stream>>>(gcur);
    k_bucketA<<<ABLK, B, 0, stream>>>(ei, gcur, bucket);
    k_bucketB<<<NBUCKET, B, 0, stream>>>(gcur, bucket, offs, dinv, csr2);

    // ---- conv layers (MFMA split-bf16 GEMM + gather-aggregate) ----
    k_mfma<1><<<MGRID, B, 0, stream>>>(x,    Wp + 0*32768, imp,     dinv, nullptr, (void*)bufYt);
    k_aggregate<<<(NNODES/16)*4, B, 0, stream>>>(bufYt, dinv, offs, csr2, b1, bufH);
    k_mfma<1><<<MGRID, B, 0, stream>>>(bufH, Wp + 1*32768, nullptr, dinv, nullptr, (void*)bufYt);
    k_aggregate<<<(NNODES/16)*4, B, 0, stream>>>(bufYt, dinv, offs, csr2, b2, bufH);
    k_mfma<1><<<MGRID, B, 0, stream>>>(bufH, Wp + 2*32768, nullptr, dinv, nullptr, (void*)bufYt);
    k_aggregate<<<(NNODES/16)*4, B, 0, stream>>>(bufYt, dinv, offs, csr2, b3, bufH);

    // ---- h = gelu(h @ lw1 + lb1) ----
    k_mfma<0><<<MGRID, B, 0, stream>>>(bufH, Wp + 3*32768, nullptr, nullptr, lb1, (void*)bufY);
    // ---- out = h @ lw2 + lb2 ----
    k_gemm16<<<NNODES/16, B, 0, stream>>>(bufY, lw2, lb2, out);
}

// Round 9
// 346.726 us; speedup vs baseline: 1.2420x; 1.0402x over previous
//
#include <hip/hip_runtime.h>
#include <math.h>

#define NNODES 50000
#define NEDGES 800000
#define FDIM 128
#define NBUCKET 196     // buckets of 256 nodes: 196*256 = 50176 >= 50000
#define BCAP 6144       // capacity per bucket (mean 4082, +32 sigma)
#define ABLK 261        // pass-A workgroups
#define EPWA 3072       // edges per pass-A wg (261*3072 >= 800000)
#define MGRID 782       // ceil(50000/64) MFMA-GEMM blocks

typedef unsigned short ushortT;
typedef unsigned int uintT;
typedef __attribute__((ext_vector_type(8))) short short8;
typedef __attribute__((ext_vector_type(4))) float floatx4;

__device__ __forceinline__ float gelu_erf(float x){
    return 0.5f * x * (1.0f + erff(x * 0.70710678118654752f));
}
// bf16 helpers
__device__ __forceinline__ float bflo(uintT u){ return __uint_as_float(u << 16); }
__device__ __forceinline__ float bfhi(uintT u){ return __uint_as_float(u & 0xFFFF0000u); }
__device__ __forceinline__ ushortT f2bf(float f){
    uintT u = __float_as_uint(f);
    return (ushortT)((u + 0x7FFFu + ((u >> 16) & 1u)) >> 16);   // RNE
}
// truncation split: f = hi + lo_resid; both bf16 (trunc). Residual error ~2^-16 rel.
__device__ __forceinline__ void split_bf16(float f, ushortT& hi, ushortT& lo){
    uintT u = __float_as_uint(f);
    hi = (ushortT)(u >> 16);
    float fhi = __uint_as_float(u & 0xFFFF0000u);
    lo = (ushortT)(__float_as_uint(f - fhi) >> 16);
}

// ---------------- CSR build ----------------
__global__ void k_zero(int* __restrict__ gcur){
    if (threadIdx.x < NBUCKET) gcur[threadIdx.x] = 0;
}

__global__ __launch_bounds__(256) void k_bucketA(const int* __restrict__ ei,
                                                 int* __restrict__ gcur,
                                                 uintT* __restrict__ bucket){
    __shared__ int hist[NBUCKET];
    __shared__ int base[NBUCKET];
    int t = threadIdx.x;
    if (t < NBUCKET) hist[t] = 0;
    __syncthreads();
    int e0 = blockIdx.x * EPWA;
    int cr_c[12], cr_r[12];
    #pragma unroll
    for (int p = 0; p < 12; p++){
        int e = e0 + p*256 + t;
        if (e < NEDGES){
            cr_r[p] = ei[e];
            cr_c[p] = ei[NEDGES + e];
            atomicAdd(&hist[cr_c[p] >> 8], 1);
        } else cr_c[p] = -1;
    }
    __syncthreads();
    if (t < NBUCKET){
        base[t] = atomicAdd(&gcur[t], hist[t]);
        hist[t] = 0;   // reuse as local cursor
    }
    __syncthreads();
    #pragma unroll
    for (int p = 0; p < 12; p++){
        int c = cr_c[p];
        if (c >= 0){
            int b = c >> 8;
            int lp = atomicAdd(&hist[b], 1);
            bucket[(size_t)b*BCAP + base[b] + lp] = ((uintT)c << 16) | (uintT)cr_r[p];
        }
    }
}

__global__ __launch_bounds__(256) void k_bucketB(const int* __restrict__ gcur,
                                                 const uintT* __restrict__ bucket,
                                                 int* __restrict__ offs,
                                                 float* __restrict__ dinv,
                                                 ushortT* __restrict__ csr2){
    __shared__ int sm[256];
    __shared__ int hist[256];
    __shared__ int lcur[256];
    int b = blockIdx.x;
    int t = threadIdx.x;
    int n0 = b << 8;

    int gv = (t < NBUCKET) ? gcur[t] : 0;
    sm[t] = gv;
    __syncthreads();
    for (int off = 1; off < 256; off <<= 1){
        int tv = (t >= off) ? sm[t-off] : 0;
        __syncthreads();
        sm[t] += tv;
        __syncthreads();
    }
    __shared__ int bbase_s;
    if (t == b) bbase_s = sm[t] - gv;
    hist[t] = 0;
    __syncthreads();
    int bbase = bbase_s;
    int count = gcur[b];
    const uintT* src = bucket + (size_t)b*BCAP;

    for (int i = t; i < count; i += 256)
        atomicAdd(&hist[(src[i] >> 16) & 255], 1);
    __syncthreads();

    int v = hist[t];
    sm[t] = v;
    __syncthreads();
    for (int off = 1; off < 256; off <<= 1){
        int tv = (t >= off) ? sm[t-off] : 0;
        __syncthreads();
        sm[t] += tv;
        __syncthreads();
    }
    int excl = bbase + sm[t] - v;
    int node = n0 + t;
    if (node <= NNODES) offs[node] = excl;
    if (node < NNODES) dinv[node] = rsqrtf((float)(v + 1));
    if (b == NBUCKET-1 && t == 255) offs[NNODES] = NEDGES;
    lcur[t] = excl;
    __syncthreads();

    for (int i = t; i < count; i += 256){
        uintT e = src[i];
        int pos = atomicAdd(&lcur[(e >> 16) & 255], 1);
        csr2[pos] = (ushortT)(e & 0xFFFFu);
    }
}

// ---------------- weight prepack: fp32 [128][128] -> bf16 hi/lo planes in B-frag order ----
__global__ __launch_bounds__(256) void k_packW(const float* __restrict__ Wa,
                                               const float* __restrict__ Wb,
                                               const float* __restrict__ Wc,
                                               const float* __restrict__ Wd,
                                               ushortT* __restrict__ Wp){
    int l = blockIdx.x;
    const float* W = (l==0) ? Wa : (l==1) ? Wb : (l==2) ? Wc : Wd;
    ushortT* hiP = Wp + (size_t)l*2*16384;
    ushortT* loP = hiP + 16384;
    for (int idx = threadIdx.x; idx < 16384; idx += 256){
        int k = idx >> 7, n = idx & 127;
        ushortT hi, lo;
        split_bf16(W[idx], hi, lo);
        int kc = k >> 5, quad = (k >> 3) & 3, j = k & 7;
        int nt = n >> 4, lane = (n & 15) + (quad << 4);
        int off = ((kc*8 + nt)*64 + lane)*8 + j;
        hiP[off] = hi;
        loP[off] = lo;
    }
}

// ---------------- MFMA GEMM [nrows,128] x [128,128], split-bf16 (bf16x3) -------------
// 64 rows/block (4 waves x 16). A staged in LDS (coalesced), frags from LDS.
// A-frag: row=lane&15, k=quad*8+j. D: col=lane&15, row=quad*4+reg.
// OUTMODE 1: Y bf16 chunk-transposed (nontemporal), scaled by dinv[row].
// OUTMODE 0: fp32 row-major +bias +gelu.
template<int OUTMODE>
__global__ __launch_bounds__(256) void k_mfma(const float* __restrict__ A,
                                              const ushortT* __restrict__ Wp,
                                              const float* __restrict__ scale,
                                              const float* __restrict__ dinv,
                                              const float* __restrict__ bias,
                                              void* __restrict__ Yout){
    __shared__ float As[64*132];
    int t = threadIdx.x;
    int wave = t >> 6, lane = t & 63;
    int r = lane & 15, quad = lane >> 4;
    int row0 = blockIdx.x*64;
    int m0 = row0 + wave*16;
    const ushortT* WpLo = Wp + 16384;

    // stage A tile (64x128 fp32) coalesced; apply scale (layer 1) here
    #pragma unroll
    for (int p = 0; p < 8; p++){
        int idx = p*256 + t;
        int rr = idx >> 5;          // 0..63
        int c4 = idx & 31;          // col group (of 4)
        int gr = row0 + rr;
        float4 v = make_float4(0.f,0.f,0.f,0.f);
        if (gr < NNODES) v = *(const float4*)&A[(size_t)gr*FDIM + c4*4];
        if (scale){
            float4 s = *(const float4*)&scale[c4*4];
            v.x*=s.x; v.y*=s.y; v.z*=s.z; v.w*=s.w;
        }
        *(float4*)&As[rr*132 + c4*4] = v;
    }
    __syncthreads();

    floatx4 acc[8];
    #pragma unroll
    for (int nt = 0; nt < 8; nt++) acc[nt] = (floatx4){0.f,0.f,0.f,0.f};

    int arl = wave*16 + r;          // local row in As
    #pragma unroll
    for (int kc = 0; kc < 4; kc++){
        int kb = kc*32 + quad*8;
        float4 a0 = *(const float4*)&As[arl*132 + kb];
        float4 a1 = *(const float4*)&As[arl*132 + kb + 4];
        float av[8] = {a0.x, a0.y, a0.z, a0.w, a1.x, a1.y, a1.z, a1.w};
        short8 ahi, alo;
        #pragma unroll
        for (int e = 0; e < 8; e++){
            ushortT h, l;
            split_bf16(av[e], h, l);
            ahi[e] = (short)h;
            alo[e] = (short)l;
        }
        #pragma unroll
        for (int nt = 0; nt < 8; nt++){
            size_t boff = (size_t)(((kc*8 + nt)*64 + lane))*8;
            short8 bhi = *(const short8*)&Wp[boff];
            short8 blo = *(const short8*)&WpLo[boff];
            acc[nt] = __builtin_amdgcn_mfma_f32_16x16x32_bf16(ahi, bhi, acc[nt], 0, 0, 0);
            acc[nt] = __builtin_amdgcn_mfma_f32_16x16x32_bf16(alo, bhi, acc[nt], 0, 0, 0);
            acc[nt] = __builtin_amdgcn_mfma_f32_16x16x32_bf16(ahi, blo, acc[nt], 0, 0, 0);
        }
    }

    int orow0 = m0 + quad*4;
    if (OUTMODE == 1){
        float4 dv = *(const float4*)&dinv[orow0];
        float dva[4] = {dv.x, dv.y, dv.z, dv.w};
        ushortT* Yb = (ushortT*)Yout;
        #pragma unroll
        for (int nt = 0; nt < 8; nt++){
            int n = nt*16 + r;
            int chunk = n >> 5, o = n & 31;
            #pragma unroll
            for (int reg = 0; reg < 4; reg++){
                int orow = orow0 + reg;
                if (orow < NNODES){
                    float v = acc[nt][reg] * dva[reg];
                    __builtin_nontemporal_store(f2bf(v),
                        &Yb[((size_t)chunk*NNODES + orow)*32 + o]);
                }
            }
        }
    } else {
        float* Yf = (float*)Yout;
        #pragma unroll
        for (int nt = 0; nt < 8; nt++){
            int n = nt*16 + r;
            float bv = bias[n];
            #pragma unroll
            for (int reg = 0; reg < 4; reg++){
                int orow = orow0 + reg;
                if (orow < NNODES){
                    Yf[(size_t)orow*FDIM + n] = gelu_erf(acc[nt][reg] + bv);
                }
            }
        }
    }
}

// ---------------- sharded aggregation (unroll 8 for MLP) ----------------
__global__ __launch_bounds__(256) void k_aggregate(const ushortT* __restrict__ Yt,
                                                   const float* __restrict__ dinv,
                                                   const int* __restrict__ offs,
                                                   const ushortT* __restrict__ csr2,
                                                   const float* __restrict__ bias,
                                                   float* __restrict__ Hout){
    int bid = blockIdx.x;
    int chunk = bid & 3;
    int node = (bid >> 2) * 16 + (threadIdx.x >> 4);
    int lane = threadIdx.x & 15;
    const uintT* Yc = (const uintT*)Yt + (size_t)chunk * NNODES * 16;

    uintT a0 = Yc[node*16 + lane];
    float2 acc;
    acc.x = bflo(a0);
    acc.y = bfhi(a0);
    int e0 = offs[node], e1 = offs[node+1];
    int e = e0;
    for (; e + 7 < e1; e += 8){
        int r0 = csr2[e+0];
        int r1 = csr2[e+1];
        int r2 = csr2[e+2];
        int r3 = csr2[e+3];
        int r4 = csr2[e+4];
        int r5 = csr2[e+5];
        int r6 = csr2[e+6];
        int r7 = csr2[e+7];
        uintT q0 = Yc[r0*16 + lane];
        uintT q1 = Yc[r1*16 + lane];
        uintT q2 = Yc[r2*16 + lane];
        uintT q3 = Yc[r3*16 + lane];
        uintT q4 = Yc[r4*16 + lane];
        uintT q5 = Yc[r5*16 + lane];
        uintT q6 = Yc[r6*16 + lane];
        uintT q7 = Yc[r7*16 + lane];
        acc.x += bflo(q0); acc.y += bfhi(q0);
        acc.x += bflo(q1); acc.y += bfhi(q1);
        acc.x += bflo(q2); acc.y += bfhi(q2);
        acc.x += bflo(q3); acc.y += bfhi(q3);
        acc.x += bflo(q4); acc.y += bfhi(q4);
        acc.x += bflo(q5); acc.y += bfhi(q5);
        acc.x += bflo(q6); acc.y += bfhi(q6);
        acc.x += bflo(q7); acc.y += bfhi(q7);
    }
    for (; e + 1 < e1; e += 2){
        int r0 = csr2[e], r1 = csr2[e+1];
        uintT q0 = Yc[r0*16 + lane];
        uintT q1 = Yc[r1*16 + lane];
        acc.x += bflo(q0); acc.y += bfhi(q0);
        acc.x += bflo(q1); acc.y += bfhi(q1);
    }
    if (e < e1){
        uintT q = Yc[csr2[e]*16 + lane];
        acc.x += bflo(q); acc.y += bfhi(q);
    }
    float dc = dinv[node];
    float2 bv = ((const float2*)bias)[chunk*16 + lane];
    acc.x = gelu_erf(fmaf(dc, acc.x, bv.x));
    acc.y = gelu_erf(fmaf(dc, acc.y, bv.y));
    float* dst = &Hout[(size_t)node*FDIM + chunk*32 + lane*2];
    __builtin_nontemporal_store(acc.x, dst);
    __builtin_nontemporal_store(acc.y, dst+1);
}

// ---------------- final GEMM [nrows,128] x [128,16] + bias ----------------
__global__ __launch_bounds__(256) void k_gemm16(const float* __restrict__ A,
                                                const float* __restrict__ W,
                                                const float* __restrict__ bias,
                                                float* __restrict__ out){
    __shared__ float Hs[16][132];
    __shared__ float Ws2[128][16];
    int row0 = blockIdx.x * 16;
    int t = threadIdx.x;
    #pragma unroll
    for (int p=0;p<8;p++){
        int lin = p*256 + t;
        int r = lin >> 7, c = lin & 127;
        Hs[r][c] = A[(row0+r)*FDIM + c];
    }
    #pragma unroll
    for (int p=0;p<8;p++){
        int lin = p*256 + t;
        Ws2[lin>>4][lin&15] = W[lin];
    }
    __syncthreads();
    int il = t >> 4, j = t & 15;
    float acc = bias[j];
    #pragma unroll
    for (int k=0;k<FDIM;k++) acc = fmaf(Hs[il][k], Ws2[k][j], acc);
    out[(row0+il)*16 + j] = acc;
}

extern "C" void kernel_launch(void* const* d_in, const int* in_sizes, int n_in,
                              void* d_out, int out_size, void* d_ws, size_t ws_size,
                              hipStream_t stream) {
    const float* x    = (const float*)d_in[0];
    const int*   ei   = (const int*)d_in[1];
    const float* imp  = (const float*)d_in[2];
    const float* W1   = (const float*)d_in[3];
    const float* b1   = (const float*)d_in[4];
    const float* W2   = (const float*)d_in[5];
    const float* b2   = (const float*)d_in[6];
    const float* W3   = (const float*)d_in[7];
    const float* b3   = (const float*)d_in[8];
    const float* lw1  = (const float*)d_in[9];
    const float* lb1  = (const float*)d_in[10];
    const float* lw2  = (const float*)d_in[11];
    const float* lb2  = (const float*)d_in[12];
    float* out = (float*)d_out;

    // workspace layout (units of 4 bytes)
    int*   offs   = (int*)d_ws;                          // 50001 (pad to 50048)
    int*   gcur   = (int*)d_ws + 50048;                  // 196 (pad to 256)
    float* dinv   = (float*)d_ws + 50304;                // 50000 (+pad)
    ushortT* csr2 = (ushortT*)((int*)d_ws + 100480);     // 800000 ushort (1.6 MB)
    uintT* bucket = (uintT*)((int*)d_ws + 500480);       // 196*6144 uint (4.8 MB)
    ushortT* Wp   = (ushortT*)((int*)d_ws + 1704704);    // 4 layers * 2 planes * 16384 ushort
    ushortT* bufYt= (ushortT*)((int*)d_ws + 1770240);    // 50000*128 bf16 transposed (12.8 MB)
    float* bufY   = (float*)d_ws + 1770240;              // alias: fp32 lw1 output (used after Yt dead)
    float* bufH   = (float*)d_ws + 8170240;              // N*128 fp32 (25.6 MB)

    dim3 B(256);
    // ---- weight prepack + CSR build ----
    k_packW  <<<4, B, 0, stream>>>(W1, W2, W3, lw1, Wp);
    k_zero   <<<1, B, 0, stream>>>(gcur);
    k_bucketA<<<ABLK, B, 0, stream>>>(ei, gcur, bucket);
    k_bucketB<<<NBUCKET, B, 0, stream>>>(gcur, bucket, offs, dinv, csr2);

    // ---- conv layers (MFMA split-bf16 GEMM + gather-aggregate) ----
    k_mfma<1><<<MGRID, B, 0, stream>>>(x,    Wp + 0*32768, imp,     dinv, nullptr, (void*)bufYt);
    k_aggregate<<<(NNODES/16)*4, B, 0, stream>>>(bufYt, dinv, offs, csr2, b1, bufH);
    k_mfma<1><<<MGRID, B, 0, stream>>>(bufH, Wp + 1*32768, nullptr, dinv, nullptr, (void*)bufYt);
    k_aggregate<<<(NNODES/16)*4, B, 0, stream>>>(bufYt, dinv, offs, csr2, b2, bufH);
    k_mfma<1><<<MGRID, B, 0, stream>>>(bufH, Wp + 2*32768, nullptr, dinv, nullptr, (void*)bufYt);
    k_aggregate<<<(NNODES/16)*4, B, 0, stream>>>(bufYt, dinv, offs, csr2, b3, bufH);

    // ---- h = gelu(h @ lw1 + lb1) ----
    k_mfma<0><<<MGRID, B, 0, stream>>>(bufH, Wp + 3*32768, nullptr, nullptr, lb1, (void*)bufY);
    // ---- out = h @ lw2 + lb2 ----
    k_gemm16<<<NNODES/16, B, 0, stream>>>(bufY, lw2, lb2, out);
}

// Round 10
// 339.798 us; speedup vs baseline: 1.2674x; 1.0204x over previous
//
#include <hip/hip_runtime.h>
#include <math.h>

#define NNODES 50000
#define NEDGES 800000
#define FDIM 128
#define NBUCKET 196     // buckets of 256 nodes: 196*256 = 50176 >= 50000
#define BCAP 6144       // capacity per bucket (mean 4082, +32 sigma)
#define ABLK 261        // pass-A workgroups
#define EPWA 3072       // edges per pass-A wg (261*3072 >= 800000)
#define MGRID 782       // ceil(50000/64) MFMA-GEMM blocks

typedef unsigned short ushortT;
typedef unsigned int uintT;
typedef __attribute__((ext_vector_type(8))) short short8;
typedef __attribute__((ext_vector_type(4))) float floatx4;

__device__ __forceinline__ float gelu_erf(float x){
    return 0.5f * x * (1.0f + erff(x * 0.70710678118654752f));
}
// bf16 helpers
__device__ __forceinline__ float bflo(uintT u){ return __uint_as_float(u << 16); }
__device__ __forceinline__ float bfhi(uintT u){ return __uint_as_float(u & 0xFFFF0000u); }
__device__ __forceinline__ ushortT f2bf(float f){
    uintT u = __float_as_uint(f);
    return (ushortT)((u + 0x7FFFu + ((u >> 16) & 1u)) >> 16);   // RNE
}
// truncation split: f = hi + lo_resid; both bf16 (trunc). Residual error ~2^-16 rel.
__device__ __forceinline__ void split_bf16(float f, ushortT& hi, ushortT& lo){
    uintT u = __float_as_uint(f);
    hi = (ushortT)(u >> 16);
    float fhi = __uint_as_float(u & 0xFFFF0000u);
    lo = (ushortT)(__float_as_uint(f - fhi) >> 16);
}

// ---------------- CSR build ----------------
__global__ void k_zero(int* __restrict__ gcur){
    if (threadIdx.x < NBUCKET) gcur[threadIdx.x] = 0;
}

__global__ __launch_bounds__(256) void k_bucketA(const int* __restrict__ ei,
                                                 int* __restrict__ gcur,
                                                 uintT* __restrict__ bucket){
    __shared__ int hist[NBUCKET];
    __shared__ int base[NBUCKET];
    int t = threadIdx.x;
    if (t < NBUCKET) hist[t] = 0;
    __syncthreads();
    int e0 = blockIdx.x * EPWA;
    int cr_c[12], cr_r[12];
    #pragma unroll
    for (int p = 0; p < 12; p++){
        int e = e0 + p*256 + t;
        if (e < NEDGES){
            cr_r[p] = ei[e];
            cr_c[p] = ei[NEDGES + e];
            atomicAdd(&hist[cr_c[p] >> 8], 1);
        } else cr_c[p] = -1;
    }
    __syncthreads();
    if (t < NBUCKET){
        base[t] = atomicAdd(&gcur[t], hist[t]);
        hist[t] = 0;   // reuse as local cursor
    }
    __syncthreads();
    #pragma unroll
    for (int p = 0; p < 12; p++){
        int c = cr_c[p];
        if (c >= 0){
            int b = c >> 8;
            int lp = atomicAdd(&hist[b], 1);
            bucket[(size_t)b*BCAP + base[b] + lp] = ((uintT)c << 16) | (uintT)cr_r[p];
        }
    }
}

__global__ __launch_bounds__(256) void k_bucketB(const int* __restrict__ gcur,
                                                 const uintT* __restrict__ bucket,
                                                 int* __restrict__ offs,
                                                 float* __restrict__ dinv,
                                                 ushortT* __restrict__ csr2){
    __shared__ int sm[256];
    __shared__ int hist[256];
    __shared__ int lcur[256];
    int b = blockIdx.x;
    int t = threadIdx.x;
    int n0 = b << 8;

    int gv = (t < NBUCKET) ? gcur[t] : 0;
    sm[t] = gv;
    __syncthreads();
    for (int off = 1; off < 256; off <<= 1){
        int tv = (t >= off) ? sm[t-off] : 0;
        __syncthreads();
        sm[t] += tv;
        __syncthreads();
    }
    __shared__ int bbase_s;
    if (t == b) bbase_s = sm[t] - gv;
    hist[t] = 0;
    __syncthreads();
    int bbase = bbase_s;
    int count = gcur[b];
    const uintT* src = bucket + (size_t)b*BCAP;

    for (int i = t; i < count; i += 256)
        atomicAdd(&hist[(src[i] >> 16) & 255], 1);
    __syncthreads();

    int v = hist[t];
    sm[t] = v;
    __syncthreads();
    for (int off = 1; off < 256; off <<= 1){
        int tv = (t >= off) ? sm[t-off] : 0;
        __syncthreads();
        sm[t] += tv;
        __syncthreads();
    }
    int excl = bbase + sm[t] - v;
    int node = n0 + t;
    if (node <= NNODES) offs[node] = excl;
    if (node < NNODES) dinv[node] = rsqrtf((float)(v + 1));
    if (b == NBUCKET-1 && t == 255) offs[NNODES] = NEDGES;
    lcur[t] = excl;
    __syncthreads();

    for (int i = t; i < count; i += 256){
        uintT e = src[i];
        int pos = atomicAdd(&lcur[(e >> 16) & 255], 1);
        csr2[pos] = (ushortT)(e & 0xFFFFu);
    }
}

// ---------------- weight prepack: fp32 [128][128] -> bf16 hi/lo planes in B-frag order ----
// B-frag for mfma_f32_16x16x32_bf16: lane holds B[k=quad*8+j][n=(lane&15)+nt*16], j=0..7.
// Packed offset: ((kc*8+nt)*64 + lane)*8 + j     (kc = k>>5, quad = (k>>3)&3)
__global__ __launch_bounds__(256) void k_packW(const float* __restrict__ Wa,
                                               const float* __restrict__ Wb,
                                               const float* __restrict__ Wc,
                                               const float* __restrict__ Wd,
                                               ushortT* __restrict__ Wp){
    int l = blockIdx.x;
    const float* W = (l==0) ? Wa : (l==1) ? Wb : (l==2) ? Wc : Wd;
    ushortT* hiP = Wp + (size_t)l*2*16384;
    ushortT* loP = hiP + 16384;
    for (int idx = threadIdx.x; idx < 16384; idx += 256){
        int k = idx >> 7, n = idx & 127;
        ushortT hi, lo;
        split_bf16(W[idx], hi, lo);
        int kc = k >> 5, quad = (k >> 3) & 3, j = k & 7;
        int nt = n >> 4, lane = (n & 15) + (quad << 4);
        int off = ((kc*8 + nt)*64 + lane)*8 + j;
        hiP[off] = hi;
        loP[off] = lo;
    }
}

// ---------------- MFMA GEMM (fp32 A, layer 1): [N,128]x[128,128] split-bf16 x3 -------
// A staged in LDS (coalesced), frags from LDS. Out: Yt bf16 chunk-transposed * dinv.
__global__ __launch_bounds__(256) void k_mfma_f32(const float* __restrict__ A,
                                                  const ushortT* __restrict__ Wp,
                                                  const float* __restrict__ scale,
                                                  const float* __restrict__ dinv,
                                                  ushortT* __restrict__ Yb){
    __shared__ float As[64*132];
    int t = threadIdx.x;
    int wave = t >> 6, lane = t & 63;
    int r = lane & 15, quad = lane >> 4;
    int row0 = blockIdx.x*64;
    int m0 = row0 + wave*16;
    const ushortT* WpLo = Wp + 16384;

    #pragma unroll
    for (int p = 0; p < 8; p++){
        int idx = p*256 + t;
        int rr = idx >> 5;
        int c4 = idx & 31;
        int gr = row0 + rr;
        float4 v = make_float4(0.f,0.f,0.f,0.f);
        if (gr < NNODES) v = *(const float4*)&A[(size_t)gr*FDIM + c4*4];
        float4 s = *(const float4*)&scale[c4*4];
        v.x*=s.x; v.y*=s.y; v.z*=s.z; v.w*=s.w;
        *(float4*)&As[rr*132 + c4*4] = v;
    }
    __syncthreads();

    floatx4 acc[8];
    #pragma unroll
    for (int nt = 0; nt < 8; nt++) acc[nt] = (floatx4){0.f,0.f,0.f,0.f};

    int arl = wave*16 + r;
    #pragma unroll
    for (int kc = 0; kc < 4; kc++){
        int kb = kc*32 + quad*8;
        float4 a0 = *(const float4*)&As[arl*132 + kb];
        float4 a1 = *(const float4*)&As[arl*132 + kb + 4];
        float av[8] = {a0.x, a0.y, a0.z, a0.w, a1.x, a1.y, a1.z, a1.w};
        short8 ahi, alo;
        #pragma unroll
        for (int e = 0; e < 8; e++){
            ushortT h, l;
            split_bf16(av[e], h, l);
            ahi[e] = (short)h;
            alo[e] = (short)l;
        }
        #pragma unroll
        for (int nt = 0; nt < 8; nt++){
            size_t boff = (size_t)(((kc*8 + nt)*64 + lane))*8;
            short8 bhi = *(const short8*)&Wp[boff];
            short8 blo = *(const short8*)&WpLo[boff];
            acc[nt] = __builtin_amdgcn_mfma_f32_16x16x32_bf16(ahi, bhi, acc[nt], 0, 0, 0);
            acc[nt] = __builtin_amdgcn_mfma_f32_16x16x32_bf16(alo, bhi, acc[nt], 0, 0, 0);
            acc[nt] = __builtin_amdgcn_mfma_f32_16x16x32_bf16(ahi, blo, acc[nt], 0, 0, 0);
        }
    }

    int orow0 = m0 + quad*4;
    float4 dv = *(const float4*)&dinv[orow0];
    float dva[4] = {dv.x, dv.y, dv.z, dv.w};
    #pragma unroll
    for (int nt = 0; nt < 8; nt++){
        int n = nt*16 + r;
        int chunk = n >> 5, o = n & 31;
        #pragma unroll
        for (int reg = 0; reg < 4; reg++){
            int orow = orow0 + reg;
            if (orow < NNODES){
                float v = acc[nt][reg] * dva[reg];
                __builtin_nontemporal_store(f2bf(v),
                    &Yb[((size_t)chunk*NNODES + orow)*32 + o]);
            }
        }
    }
}

// ---------------- MFMA GEMM (bf16 A, layers 2/3/lw1): zero-LDS, split-W x2 ----------
// A bf16 row-major: lane's frag = 8 contiguous bf16 at A[arow*128 + kc*32 + quad*8]
// (16-B aligned, 64B line feeds 4 quads). OUTMODE 1: Yt bf16 chunk-transposed * dinv.
// OUTMODE 0: bf16 row-major +bias +gelu.
template<int OUTMODE>
__global__ __launch_bounds__(256) void k_mfma_b16(const ushortT* __restrict__ Ab,
                                                  const ushortT* __restrict__ Wp,
                                                  const float* __restrict__ dinv,
                                                  const float* __restrict__ bias,
                                                  ushortT* __restrict__ Yb){
    int t = threadIdx.x;
    int wave = t >> 6, lane = t & 63;
    int r = lane & 15, quad = lane >> 4;
    int m0 = blockIdx.x*64 + wave*16;
    int arow = m0 + r;
    if (arow >= NNODES) arow = NNODES - 1;
    const ushortT* WpLo = Wp + 16384;

    floatx4 acc[8];
    #pragma unroll
    for (int nt = 0; nt < 8; nt++) acc[nt] = (floatx4){0.f,0.f,0.f,0.f};

    short8 afr[4];
    #pragma unroll
    for (int kc = 0; kc < 4; kc++)
        afr[kc] = *(const short8*)&Ab[(size_t)arow*FDIM + kc*32 + quad*8];

    #pragma unroll
    for (int kc = 0; kc < 4; kc++){
        #pragma unroll
        for (int nt = 0; nt < 8; nt++){
            size_t boff = (size_t)(((kc*8 + nt)*64 + lane))*8;
            short8 bhi = *(const short8*)&Wp[boff];
            short8 blo = *(const short8*)&WpLo[boff];
            acc[nt] = __builtin_amdgcn_mfma_f32_16x16x32_bf16(afr[kc], bhi, acc[nt], 0, 0, 0);
            acc[nt] = __builtin_amdgcn_mfma_f32_16x16x32_bf16(afr[kc], blo, acc[nt], 0, 0, 0);
        }
    }

    int orow0 = m0 + quad*4;
    if (OUTMODE == 1){
        float4 dv = *(const float4*)&dinv[orow0];
        float dva[4] = {dv.x, dv.y, dv.z, dv.w};
        #pragma unroll
        for (int nt = 0; nt < 8; nt++){
            int n = nt*16 + r;
            int chunk = n >> 5, o = n & 31;
            #pragma unroll
            for (int reg = 0; reg < 4; reg++){
                int orow = orow0 + reg;
                if (orow < NNODES){
                    float v = acc[nt][reg] * dva[reg];
                    __builtin_nontemporal_store(f2bf(v),
                        &Yb[((size_t)chunk*NNODES + orow)*32 + o]);
                }
            }
        }
    } else {
        #pragma unroll
        for (int nt = 0; nt < 8; nt++){
            int n = nt*16 + r;
            float bv = bias[n];
            #pragma unroll
            for (int reg = 0; reg < 4; reg++){
                int orow = orow0 + reg;
                if (orow < NNODES){
                    float v = gelu_erf(acc[nt][reg] + bv);
                    __builtin_nontemporal_store(f2bf(v), &Yb[(size_t)orow*FDIM + n]);
                }
            }
        }
    }
}

// ---------------- sharded aggregation (bf16 out) ----------------
__global__ __launch_bounds__(256) void k_aggregate(const ushortT* __restrict__ Yt,
                                                   const float* __restrict__ dinv,
                                                   const int* __restrict__ offs,
                                                   const ushortT* __restrict__ csr2,
                                                   const float* __restrict__ bias,
                                                   ushortT* __restrict__ Hout){
    int bid = blockIdx.x;
    int chunk = bid & 3;
    int node = (bid >> 2) * 16 + (threadIdx.x >> 4);
    int lane = threadIdx.x & 15;
    const uintT* Yc = (const uintT*)Yt + (size_t)chunk * NNODES * 16;

    uintT a0 = Yc[node*16 + lane];
    float2 acc;
    acc.x = bflo(a0);
    acc.y = bfhi(a0);
    int e0 = offs[node], e1 = offs[node+1];
    int e = e0;
    for (; e + 7 < e1; e += 8){
        int r0 = csr2[e+0];
        int r1 = csr2[e+1];
        int r2 = csr2[e+2];
        int r3 = csr2[e+3];
        int r4 = csr2[e+4];
        int r5 = csr2[e+5];
        int r6 = csr2[e+6];
        int r7 = csr2[e+7];
        uintT q0 = Yc[r0*16 + lane];
        uintT q1 = Yc[r1*16 + lane];
        uintT q2 = Yc[r2*16 + lane];
        uintT q3 = Yc[r3*16 + lane];
        uintT q4 = Yc[r4*16 + lane];
        uintT q5 = Yc[r5*16 + lane];
        uintT q6 = Yc[r6*16 + lane];
        uintT q7 = Yc[r7*16 + lane];
        acc.x += bflo(q0); acc.y += bfhi(q0);
        acc.x += bflo(q1); acc.y += bfhi(q1);
        acc.x += bflo(q2); acc.y += bfhi(q2);
        acc.x += bflo(q3); acc.y += bfhi(q3);
        acc.x += bflo(q4); acc.y += bfhi(q4);
        acc.x += bflo(q5); acc.y += bfhi(q5);
        acc.x += bflo(q6); acc.y += bfhi(q6);
        acc.x += bflo(q7); acc.y += bfhi(q7);
    }
    for (; e + 1 < e1; e += 2){
        int r0 = csr2[e], r1 = csr2[e+1];
        uintT q0 = Yc[r0*16 + lane];
        uintT q1 = Yc[r1*16 + lane];
        acc.x += bflo(q0); acc.y += bfhi(q0);
        acc.x += bflo(q1); acc.y += bfhi(q1);
    }
    if (e < e1){
        uintT q = Yc[csr2[e]*16 + lane];
        acc.x += bflo(q); acc.y += bfhi(q);
    }
    float dc = dinv[node];
    float2 bv = ((const float2*)bias)[chunk*16 + lane];
    acc.x = gelu_erf(fmaf(dc, acc.x, bv.x));
    acc.y = gelu_erf(fmaf(dc, acc.y, bv.y));
    uintT packed = (uintT)f2bf(acc.x) | ((uintT)f2bf(acc.y) << 16);
    uintT* dst = (uintT*)&Hout[(size_t)node*FDIM + chunk*32 + lane*2];
    __builtin_nontemporal_store(packed, dst);
}

// ---------------- final GEMM [nrows,128](bf16) x [128,16] + bias ----------------
__global__ __launch_bounds__(256) void k_gemm16(const ushortT* __restrict__ A,
                                                const float* __restrict__ W,
                                                const float* __restrict__ bias,
                                                float* __restrict__ out){
    __shared__ float Hs[16][132];
    __shared__ float Ws2[128][16];
    int row0 = blockIdx.x * 16;
    int t = threadIdx.x;
    const uintT* A2 = (const uintT*)A;
    #pragma unroll
    for (int p=0;p<4;p++){
        int idx = p*256 + t;            // 16*64 = 1024 uints
        int r = idx >> 6, c2 = idx & 63;
        uintT u = A2[(size_t)(row0+r)*64 + c2];
        Hs[r][c2*2]   = bflo(u);
        Hs[r][c2*2+1] = bfhi(u);
    }
    #pragma unroll
    for (int p=0;p<8;p++){
        int lin = p*256 + t;
        Ws2[lin>>4][lin&15] = W[lin];
    }
    __syncthreads();
    int il = t >> 4, j = t & 15;
    float acc = bias[j];
    #pragma unroll
    for (int k=0;k<FDIM;k++) acc = fmaf(Hs[il][k], Ws2[k][j], acc);
    out[(row0+il)*16 + j] = acc;
}

extern "C" void kernel_launch(void* const* d_in, const int* in_sizes, int n_in,
                              void* d_out, int out_size, void* d_ws, size_t ws_size,
                              hipStream_t stream) {
    const float* x    = (const float*)d_in[0];
    const int*   ei   = (const int*)d_in[1];
    const float* imp  = (const float*)d_in[2];
    const float* W1   = (const float*)d_in[3];
    const float* b1   = (const float*)d_in[4];
    const float* W2   = (const float*)d_in[5];
    const float* b2   = (const float*)d_in[6];
    const float* W3   = (const float*)d_in[7];
    const float* b3   = (const float*)d_in[8];
    const float* lw1  = (const float*)d_in[9];
    const float* lb1  = (const float*)d_in[10];
    const float* lw2  = (const float*)d_in[11];
    const float* lb2  = (const float*)d_in[12];
    float* out = (float*)d_out;

    // workspace layout (units of 4 bytes)
    int*   offs   = (int*)d_ws;                          // 50001 (pad to 50048)
    int*   gcur   = (int*)d_ws + 50048;                  // 196 (pad to 256)
    float* dinv   = (float*)d_ws + 50304;                // 50000 (+pad to 50176)
    ushortT* csr2 = (ushortT*)((int*)d_ws + 100480);     // 800000 ushort (1.6 MB)
    uintT* bucket = (uintT*)((int*)d_ws + 500480);       // 196*6144 uint (4.8 MB)
    ushortT* Wp   = (ushortT*)((int*)d_ws + 1704704);    // 4 layers * 2 planes * 16384 ushort
    ushortT* bufYt= (ushortT*)((int*)d_ws + 1770240);    // 50000*128 bf16 chunk-transposed (12.8 MB)
    ushortT* bufPb= bufYt;                               // alias: bf16 lw1 output (Yt dead by then)
    ushortT* bufH = (ushortT*)((int*)d_ws + 8170240);    // 50000*128 bf16 row-major (12.8 MB)

    dim3 B(256);
    // ---- weight prepack + CSR build ----
    k_packW  <<<4, B, 0, stream>>>(W1, W2, W3, lw1, Wp);
    k_zero   <<<1, B, 0, stream>>>(gcur);
    k_bucketA<<<ABLK, B, 0, stream>>>(ei, gcur, bucket);
    k_bucketB<<<NBUCKET, B, 0, stream>>>(gcur, bucket, offs, dinv, csr2);

    // ---- conv layers ----
    k_mfma_f32  <<<MGRID, B, 0, stream>>>(x, Wp + 0*32768, imp, dinv, bufYt);
    k_aggregate <<<(NNODES/16)*4, B, 0, stream>>>(bufYt, dinv, offs, csr2, b1, bufH);
    k_mfma_b16<1><<<MGRID, B, 0, stream>>>(bufH, Wp + 1*32768, dinv, nullptr, bufYt);
    k_aggregate <<<(NNODES/16)*4, B, 0, stream>>>(bufYt, dinv, offs, csr2, b2, bufH);
    k_mfma_b16<1><<<MGRID, B, 0, stream>>>(bufH, Wp + 2*32768, dinv, nullptr, bufYt);
    k_aggregate <<<(NNODES/16)*4, B, 0, stream>>>(bufYt, dinv, offs, csr2, b3, bufH);

    // ---- h = gelu(h @ lw1 + lb1)  (bf16 out) ----
    k_mfma_b16<0><<<MGRID, B, 0, stream>>>(bufH, Wp + 3*32768, nullptr, lb1, bufPb);
    // ---- out = h @ lw2 + lb2 ----
    k_gemm16<<<NNODES/16, B, 0, stream>>>(bufPb, lw2, lb2, out);
}

// Round 11
// 320.291 us; speedup vs baseline: 1.3446x; 1.0609x over previous
//
#include <hip/hip_runtime.h>
#include <math.h>

#define NNODES 50000
#define NEDGES 800000
#define FDIM 128
#define NBUCKET 196     // buckets of 256 nodes: 196*256 = 50176 >= 50000
#define BCAP 6144       // capacity per bucket (mean 4082, +32 sigma)
#define ABLK 261        // pass-A workgroups
#define EPWA 3072       // edges per pass-A wg (261*3072 >= 800000)
#define MGRID 782       // ceil(50000/64) MFMA-GEMM blocks

typedef unsigned short ushortT;
typedef unsigned int uintT;
typedef __attribute__((ext_vector_type(8))) short short8;
typedef __attribute__((ext_vector_type(4))) float floatx4;

__device__ __forceinline__ float gelu_erf(float x){
    return 0.5f * x * (1.0f + erff(x * 0.70710678118654752f));
}
// bf16 helpers
__device__ __forceinline__ float bflo(uintT u){ return __uint_as_float(u << 16); }
__device__ __forceinline__ float bfhi(uintT u){ return __uint_as_float(u & 0xFFFF0000u); }
__device__ __forceinline__ ushortT f2bf(float f){
    uintT u = __float_as_uint(f);
    return (ushortT)((u + 0x7FFFu + ((u >> 16) & 1u)) >> 16);   // RNE
}
// truncation split: f = hi + lo_resid; both bf16 (trunc). Residual error ~2^-16 rel.
__device__ __forceinline__ void split_bf16(float f, ushortT& hi, ushortT& lo){
    uintT u = __float_as_uint(f);
    hi = (ushortT)(u >> 16);
    float fhi = __uint_as_float(u & 0xFFFF0000u);
    lo = (ushortT)(__float_as_uint(f - fhi) >> 16);
}

// ---------------- weight prepack + gcur zero ----------------
// blocks 0-3: 128x128 weights -> bf16 hi/lo planes in B-frag order.
// B-frag (16x16x32): lane holds B[k=quad*8+j][n=(lane&15)+nt*16], j=0..7.
//   off = ((kc*8+nt)*64 + lane)*8 + j   (kc=k>>5, quad=(k>>3)&3)
// block 4: lw2 (128x16) packed compact (nt=0): off = (kc*64+lane)*8 + j; also zeros gcur.
__global__ __launch_bounds__(256) void k_packW(const float* __restrict__ Wa,
                                               const float* __restrict__ Wb,
                                               const float* __restrict__ Wc,
                                               const float* __restrict__ Wd,
                                               const float* __restrict__ We,
                                               ushortT* __restrict__ Wp,
                                               int* __restrict__ gcur){
    int l = blockIdx.x;
    int t = threadIdx.x;
    if (l < 4){
        const float* W = (l==0) ? Wa : (l==1) ? Wb : (l==2) ? Wc : Wd;
        ushortT* hiP = Wp + (size_t)l*2*16384;
        ushortT* loP = hiP + 16384;
        for (int idx = t; idx < 16384; idx += 256){
            int k = idx >> 7, n = idx & 127;
            ushortT hi, lo;
            split_bf16(W[idx], hi, lo);
            int kc = k >> 5, quad = (k >> 3) & 3, j = k & 7;
            int nt = n >> 4, lane = (n & 15) + (quad << 4);
            int off = ((kc*8 + nt)*64 + lane)*8 + j;
            hiP[off] = hi;
            loP[off] = lo;
        }
    } else {
        if (t < NBUCKET) gcur[t] = 0;
        ushortT* hiP = Wp + (size_t)4*2*16384;
        ushortT* loP = hiP + 2048;
        for (int idx = t; idx < 2048; idx += 256){
            int k = idx >> 4, n = idx & 15;
            ushortT hi, lo;
            split_bf16(We[idx], hi, lo);
            int kc = k >> 5, quad = (k >> 3) & 3, j = k & 7;
            int lane = n + (quad << 4);
            int off = (kc*64 + lane)*8 + j;
            hiP[off] = hi;
            loP[off] = lo;
        }
    }
}

// ---------------- CSR build ----------------
__global__ __launch_bounds__(256) void k_bucketA(const int* __restrict__ ei,
                                                 int* __restrict__ gcur,
                                                 uintT* __restrict__ bucket){
    __shared__ int hist[NBUCKET];
    __shared__ int base[NBUCKET];
    int t = threadIdx.x;
    if (t < NBUCKET) hist[t] = 0;
    __syncthreads();
    int e0 = blockIdx.x * EPWA;
    int cr_c[12], cr_r[12];
    #pragma unroll
    for (int p = 0; p < 12; p++){
        int e = e0 + p*256 + t;
        if (e < NEDGES){
            cr_r[p] = ei[e];
            cr_c[p] = ei[NEDGES + e];
            atomicAdd(&hist[cr_c[p] >> 8], 1);
        } else cr_c[p] = -1;
    }
    __syncthreads();
    if (t < NBUCKET){
        base[t] = atomicAdd(&gcur[t], hist[t]);
        hist[t] = 0;   // reuse as local cursor
    }
    __syncthreads();
    #pragma unroll
    for (int p = 0; p < 12; p++){
        int c = cr_c[p];
        if (c >= 0){
            int b = c >> 8;
            int lp = atomicAdd(&hist[b], 1);
            bucket[(size_t)b*BCAP + base[b] + lp] = ((uintT)c << 16) | (uintT)cr_r[p];
        }
    }
}

__global__ __launch_bounds__(256) void k_bucketB(const int* __restrict__ gcur,
                                                 const uintT* __restrict__ bucket,
                                                 int* __restrict__ offs,
                                                 float* __restrict__ dinv,
                                                 ushortT* __restrict__ csr2){
    __shared__ int sm[256];
    __shared__ int hist[256];
    __shared__ int lcur[256];
    int b = blockIdx.x;
    int t = threadIdx.x;
    int n0 = b << 8;

    int gv = (t < NBUCKET) ? gcur[t] : 0;
    sm[t] = gv;
    __syncthreads();
    for (int off = 1; off < 256; off <<= 1){
        int tv = (t >= off) ? sm[t-off] : 0;
        __syncthreads();
        sm[t] += tv;
        __syncthreads();
    }
    __shared__ int bbase_s;
    if (t == b) bbase_s = sm[t] - gv;
    hist[t] = 0;
    __syncthreads();
    int bbase = bbase_s;
    int count = gcur[b];
    const uintT* src = bucket + (size_t)b*BCAP;

    for (int i = t; i < count; i += 256)
        atomicAdd(&hist[(src[i] >> 16) & 255], 1);
    __syncthreads();

    int v = hist[t];
    sm[t] = v;
    __syncthreads();
    for (int off = 1; off < 256; off <<= 1){
        int tv = (t >= off) ? sm[t-off] : 0;
        __syncthreads();
        sm[t] += tv;
        __syncthreads();
    }
    int excl = bbase + sm[t] - v;
    int node = n0 + t;
    if (node <= NNODES) offs[node] = excl;
    if (node < NNODES) dinv[node] = rsqrtf((float)(v + 1));
    if (b == NBUCKET-1 && t == 255) offs[NNODES] = NEDGES;
    lcur[t] = excl;
    __syncthreads();

    for (int i = t; i < count; i += 256){
        uintT e = src[i];
        int pos = atomicAdd(&lcur[(e >> 16) & 255], 1);
        csr2[pos] = (ushortT)(e & 0xFFFFu);
    }
}

// ---------------- MFMA GEMM (fp32 A, layer 1): [N,128]x[128,128] split-bf16 x3 -------
// A staged in LDS (coalesced), frags from LDS. Out: Yt bf16 2-chunk-transposed * dinv.
__global__ __launch_bounds__(256) void k_mfma_f32(const float* __restrict__ A,
                                                  const ushortT* __restrict__ Wp,
                                                  const float* __restrict__ scale,
                                                  const float* __restrict__ dinv,
                                                  ushortT* __restrict__ Yb){
    __shared__ float As[64*132];
    int t = threadIdx.x;
    int wave = t >> 6, lane = t & 63;
    int r = lane & 15, quad = lane >> 4;
    int row0 = blockIdx.x*64;
    int m0 = row0 + wave*16;
    const ushortT* WpLo = Wp + 16384;

    #pragma unroll
    for (int p = 0; p < 8; p++){
        int idx = p*256 + t;
        int rr = idx >> 5;
        int c4 = idx & 31;
        int gr = row0 + rr;
        float4 v = make_float4(0.f,0.f,0.f,0.f);
        if (gr < NNODES) v = *(const float4*)&A[(size_t)gr*FDIM + c4*4];
        float4 s = *(const float4*)&scale[c4*4];
        v.x*=s.x; v.y*=s.y; v.z*=s.z; v.w*=s.w;
        *(float4*)&As[rr*132 + c4*4] = v;
    }
    __syncthreads();

    floatx4 acc[8];
    #pragma unroll
    for (int nt = 0; nt < 8; nt++) acc[nt] = (floatx4){0.f,0.f,0.f,0.f};

    int arl = wave*16 + r;
    #pragma unroll
    for (int kc = 0; kc < 4; kc++){
        int kb = kc*32 + quad*8;
        float4 a0 = *(const float4*)&As[arl*132 + kb];
        float4 a1 = *(const float4*)&As[arl*132 + kb + 4];
        float av[8] = {a0.x, a0.y, a0.z, a0.w, a1.x, a1.y, a1.z, a1.w};
        short8 ahi, alo;
        #pragma unroll
        for (int e = 0; e < 8; e++){
            ushortT h, l;
            split_bf16(av[e], h, l);
            ahi[e] = (short)h;
            alo[e] = (short)l;
        }
        #pragma unroll
        for (int nt = 0; nt < 8; nt++){
            size_t boff = (size_t)(((kc*8 + nt)*64 + lane))*8;
            short8 bhi = *(const short8*)&Wp[boff];
            short8 blo = *(const short8*)&WpLo[boff];
            acc[nt] = __builtin_amdgcn_mfma_f32_16x16x32_bf16(ahi, bhi, acc[nt], 0, 0, 0);
            acc[nt] = __builtin_amdgcn_mfma_f32_16x16x32_bf16(alo, bhi, acc[nt], 0, 0, 0);
            acc[nt] = __builtin_amdgcn_mfma_f32_16x16x32_bf16(ahi, blo, acc[nt], 0, 0, 0);
        }
    }

    int orow0 = m0 + quad*4;
    float4 dv = *(const float4*)&dinv[orow0];
    float dva[4] = {dv.x, dv.y, dv.z, dv.w};
    #pragma unroll
    for (int nt = 0; nt < 8; nt++){
        int n = nt*16 + r;
        int chunk = n >> 6, o = n & 63;
        #pragma unroll
        for (int reg = 0; reg < 4; reg++){
            int orow = orow0 + reg;
            if (orow < NNODES){
                float v = acc[nt][reg] * dva[reg];
                __builtin_nontemporal_store(f2bf(v),
                    &Yb[((size_t)chunk*NNODES + orow)*64 + o]);
            }
        }
    }
}

// ---------------- MFMA GEMM (bf16 A, layers 2/3): zero-LDS, split-W x2 --------------
// A bf16 row-major; lane's frag = 8 contiguous bf16 (full 64B-line use per 4 quads).
// Out: Yt bf16 2-chunk-transposed * dinv (nontemporal).
__global__ __launch_bounds__(256) void k_mfma_b16(const ushortT* __restrict__ Ab,
                                                  const ushortT* __restrict__ Wp,
                                                  const float* __restrict__ dinv,
                                                  ushortT* __restrict__ Yb){
    int t = threadIdx.x;
    int wave = t >> 6, lane = t & 63;
    int r = lane & 15, quad = lane >> 4;
    int m0 = blockIdx.x*64 + wave*16;
    int arow = m0 + r;
    if (arow >= NNODES) arow = NNODES - 1;
    const ushortT* WpLo = Wp + 16384;

    floatx4 acc[8];
    #pragma unroll
    for (int nt = 0; nt < 8; nt++) acc[nt] = (floatx4){0.f,0.f,0.f,0.f};

    short8 afr[4];
    #pragma unroll
    for (int kc = 0; kc < 4; kc++)
        afr[kc] = *(const short8*)&Ab[(size_t)arow*FDIM + kc*32 + quad*8];

    #pragma unroll
    for (int kc = 0; kc < 4; kc++){
        #pragma unroll
        for (int nt = 0; nt < 8; nt++){
            size_t boff = (size_t)(((kc*8 + nt)*64 + lane))*8;
            short8 bhi = *(const short8*)&Wp[boff];
            short8 blo = *(const short8*)&WpLo[boff];
            acc[nt] = __builtin_amdgcn_mfma_f32_16x16x32_bf16(afr[kc], bhi, acc[nt], 0, 0, 0);
            acc[nt] = __builtin_amdgcn_mfma_f32_16x16x32_bf16(afr[kc], blo, acc[nt], 0, 0, 0);
        }
    }

    int orow0 = m0 + quad*4;
    float4 dv = *(const float4*)&dinv[orow0];
    float dva[4] = {dv.x, dv.y, dv.z, dv.w};
    #pragma unroll
    for (int nt = 0; nt < 8; nt++){
        int n = nt*16 + r;
        int chunk = n >> 6, o = n & 63;
        #pragma unroll
        for (int reg = 0; reg < 4; reg++){
            int orow = orow0 + reg;
            if (orow < NNODES){
                float v = acc[nt][reg] * dva[reg];
                __builtin_nontemporal_store(f2bf(v),
                    &Yb[((size_t)chunk*NNODES + orow)*64 + o]);
            }
        }
    }
}

// ---------------- fused final: out = gelu(H@lw1+lb1)@lw2 + lb2 ----------------------
// Stage 1 like k_mfma_b16; P -> bias+gelu -> bf16 LDS tile (per-wave private rows);
// stage 2: A-frags from LDS, prepacked lw2 hi/lo, D -> fp32 out.
__global__ __launch_bounds__(256) void k_mfma_final(const ushortT* __restrict__ Ab,
                                                    const ushortT* __restrict__ Wp1,
                                                    const ushortT* __restrict__ Wp2,
                                                    const float* __restrict__ lb1,
                                                    const float* __restrict__ lb2,
                                                    float* __restrict__ out){
    __shared__ ushortT Ls[64*136];
    int t = threadIdx.x;
    int wave = t >> 6, lane = t & 63;
    int r = lane & 15, quad = lane >> 4;
    int row0 = blockIdx.x*64;
    int m0 = row0 + wave*16;
    int arow = m0 + r;
    if (arow >= NNODES) arow = NNODES - 1;
    const ushortT* Wp1Lo = Wp1 + 16384;
    const ushortT* Wp2Lo = Wp2 + 2048;

    floatx4 acc[8];
    #pragma unroll
    for (int nt = 0; nt < 8; nt++) acc[nt] = (floatx4){0.f,0.f,0.f,0.f};

    short8 afr[4];
    #pragma unroll
    for (int kc = 0; kc < 4; kc++)
        afr[kc] = *(const short8*)&Ab[(size_t)arow*FDIM + kc*32 + quad*8];

    #pragma unroll
    for (int kc = 0; kc < 4; kc++){
        #pragma unroll
        for (int nt = 0; nt < 8; nt++){
            size_t boff = (size_t)(((kc*8 + nt)*64 + lane))*8;
            short8 bhi = *(const short8*)&Wp1[boff];
            short8 blo = *(const short8*)&Wp1Lo[boff];
            acc[nt] = __builtin_amdgcn_mfma_f32_16x16x32_bf16(afr[kc], bhi, acc[nt], 0, 0, 0);
            acc[nt] = __builtin_amdgcn_mfma_f32_16x16x32_bf16(afr[kc], blo, acc[nt], 0, 0, 0);
        }
    }

    // P -> gelu -> bf16 LDS (local row = wave*16 + quad*4 + reg)
    int lrow0 = wave*16 + quad*4;
    #pragma unroll
    for (int nt = 0; nt < 8; nt++){
        int n = nt*16 + r;
        float bv = lb1[n];
        #pragma unroll
        for (int reg = 0; reg < 4; reg++){
            Ls[(lrow0 + reg)*136 + n] = f2bf(gelu_erf(acc[nt][reg] + bv));
        }
    }
    __syncthreads();

    // stage 2: 64x128 @ 128x16
    floatx4 acc2 = (floatx4){0.f,0.f,0.f,0.f};
    #pragma unroll
    for (int kc = 0; kc < 4; kc++){
        short8 a2 = *(const short8*)&Ls[(wave*16 + r)*136 + kc*32 + quad*8];
        short8 bhi = *(const short8*)&Wp2[(size_t)(kc*64 + lane)*8];
        short8 blo = *(const short8*)&Wp2Lo[(size_t)(kc*64 + lane)*8];
        acc2 = __builtin_amdgcn_mfma_f32_16x16x32_bf16(a2, bhi, acc2, 0, 0, 0);
        acc2 = __builtin_amdgcn_mfma_f32_16x16x32_bf16(a2, blo, acc2, 0, 0, 0);
    }
    float bv2 = lb2[r];
    #pragma unroll
    for (int reg = 0; reg < 4; reg++){
        int orow = m0 + quad*4 + reg;
        if (orow < NNODES)
            out[(size_t)orow*16 + r] = acc2[reg] + bv2;
    }
}

// ---------------- sharded aggregation: 2 chunks x 64 feats, 32 lanes/node -----------
__global__ __launch_bounds__(256) void k_aggregate(const ushortT* __restrict__ Yt,
                                                   const float* __restrict__ dinv,
                                                   const int* __restrict__ offs,
                                                   const ushortT* __restrict__ csr2,
                                                   const float* __restrict__ bias,
                                                   ushortT* __restrict__ Hout){
    int bid = blockIdx.x;
    int chunk = bid & 1;
    int node = (bid >> 1) * 8 + (threadIdx.x >> 5);
    int lane = threadIdx.x & 31;
    const uintT* Yc = (const uintT*)Yt + (size_t)chunk * NNODES * 32;

    uintT a0 = Yc[node*32 + lane];
    float2 acc;
    acc.x = bflo(a0);
    acc.y = bfhi(a0);
    int e0 = offs[node], e1 = offs[node+1];
    int e = e0;
    for (; e + 7 < e1; e += 8){
        int r0 = csr2[e+0];
        int r1 = csr2[e+1];
        int r2 = csr2[e+2];
        int r3 = csr2[e+3];
        int r4 = csr2[e+4];
        int r5 = csr2[e+5];
        int r6 = csr2[e+6];
        int r7 = csr2[e+7];
        uintT q0 = Yc[r0*32 + lane];
        uintT q1 = Yc[r1*32 + lane];
        uintT q2 = Yc[r2*32 + lane];
        uintT q3 = Yc[r3*32 + lane];
        uintT q4 = Yc[r4*32 + lane];
        uintT q5 = Yc[r5*32 + lane];
        uintT q6 = Yc[r6*32 + lane];
        uintT q7 = Yc[r7*32 + lane];
        acc.x += bflo(q0); acc.y += bfhi(q0);
        acc.x += bflo(q1); acc.y += bfhi(q1);
        acc.x += bflo(q2); acc.y += bfhi(q2);
        acc.x += bflo(q3); acc.y += bfhi(q3);
        acc.x += bflo(q4); acc.y += bfhi(q4);
        acc.x += bflo(q5); acc.y += bfhi(q5);
        acc.x += bflo(q6); acc.y += bfhi(q6);
        acc.x += bflo(q7); acc.y += bfhi(q7);
    }
    for (; e + 1 < e1; e += 2){
        int r0 = csr2[e], r1 = csr2[e+1];
        uintT q0 = Yc[r0*32 + lane];
        uintT q1 = Yc[r1*32 + lane];
        acc.x += bflo(q0); acc.y += bfhi(q0);
        acc.x += bflo(q1); acc.y += bfhi(q1);
    }
    if (e < e1){
        uintT q = Yc[csr2[e]*32 + lane];
        acc.x += bflo(q); acc.y += bfhi(q);
    }
    float dc = dinv[node];
    float2 bv = ((const float2*)bias)[chunk*32 + lane];
    acc.x = gelu_erf(fmaf(dc, acc.x, bv.x));
    acc.y = gelu_erf(fmaf(dc, acc.y, bv.y));
    uintT packed = (uintT)f2bf(acc.x) | ((uintT)f2bf(acc.y) << 16);
    uintT* dst = (uintT*)&Hout[(size_t)node*FDIM + chunk*64 + lane*2];
    __builtin_nontemporal_store(packed, dst);
}

extern "C" void kernel_launch(void* const* d_in, const int* in_sizes, int n_in,
                              void* d_out, int out_size, void* d_ws, size_t ws_size,
                              hipStream_t stream) {
    const float* x    = (const float*)d_in[0];
    const int*   ei   = (const int*)d_in[1];
    const float* imp  = (const float*)d_in[2];
    const float* W1   = (const float*)d_in[3];
    const float* b1   = (const float*)d_in[4];
    const float* W2   = (const float*)d_in[5];
    const float* b2   = (const float*)d_in[6];
    const float* W3   = (const float*)d_in[7];
    const float* b3   = (const float*)d_in[8];
    const float* lw1  = (const float*)d_in[9];
    const float* lb1  = (const float*)d_in[10];
    const float* lw2  = (const float*)d_in[11];
    const float* lb2  = (const float*)d_in[12];
    float* out = (float*)d_out;

    // workspace layout (units of 4 bytes)
    int*   offs   = (int*)d_ws;                          // 50001 (pad to 50048)
    int*   gcur   = (int*)d_ws + 50048;                  // 196 (pad to 50304)
    float* dinv   = (float*)d_ws + 50304;                // 50000 (pad to 100480)
    ushortT* csr2 = (ushortT*)((int*)d_ws + 100480);     // 800000 ushort (1.6 MB)
    uintT* bucket = (uintT*)((int*)d_ws + 500480);       // 196*6144 uint (4.8 MB)
    ushortT* Wp   = (ushortT*)((int*)d_ws + 1704704);    // 4*32768 + 4096 ushort (~270 KB)
    ushortT* bufYt= (ushortT*)((int*)d_ws + 1772544);    // 50000*128 bf16 2-chunk-transposed
    ushortT* bufH = (ushortT*)((int*)d_ws + 4972544);    // 50000*128 bf16 row-major

    dim3 B(256);
    // ---- weight prepack (+gcur zero) + CSR build ----
    k_packW  <<<5, B, 0, stream>>>(W1, W2, W3, lw1, lw2, Wp, gcur);
    k_bucketA<<<ABLK, B, 0, stream>>>(ei, gcur, bucket);
    k_bucketB<<<NBUCKET, B, 0, stream>>>(gcur, bucket, offs, dinv, csr2);

    // ---- conv layers ----
    k_mfma_f32 <<<MGRID, B, 0, stream>>>(x, Wp + 0*32768, imp, dinv, bufYt);
    k_aggregate<<<(NNODES/8)*2, B, 0, stream>>>(bufYt, dinv, offs, csr2, b1, bufH);
    k_mfma_b16 <<<MGRID, B, 0, stream>>>(bufH, Wp + 1*32768, dinv, bufYt);
    k_aggregate<<<(NNODES/8)*2, B, 0, stream>>>(bufYt, dinv, offs, csr2, b2, bufH);
    k_mfma_b16 <<<MGRID, B, 0, stream>>>(bufH, Wp + 2*32768, dinv, bufYt);
    k_aggregate<<<(NNODES/8)*2, B, 0, stream>>>(bufYt, dinv, offs, csr2, b3, bufH);

    // ---- out = gelu(H@lw1+lb1)@lw2 + lb2 (fused) ----
    k_mfma_final<<<MGRID, B, 0, stream>>>(bufH, Wp + 3*32768, Wp + 4*32768, lb1, lb2, out);
}

// Round 12
// 318.450 us; speedup vs baseline: 1.3523x; 1.0058x over previous
//
#include <hip/hip_runtime.h>
#include <math.h>

#define NNODES 50000
#define NEDGES 800000
#define FDIM 128
#define NBUCKET 196     // buckets of 256 nodes: 196*256 = 50176 >= 50000
#define BCAP 6144       // capacity per bucket (mean 4082, +32 sigma)
#define ABLK 261        // pass-A workgroups
#define EPWA 3072       // edges per pass-A wg (261*3072 >= 800000)
#define MGRID 782       // ceil(50000/64) MFMA-GEMM blocks

typedef unsigned short ushortT;
typedef unsigned int uintT;
typedef __attribute__((ext_vector_type(8))) short short8;
typedef __attribute__((ext_vector_type(4))) float floatx4;

__device__ __forceinline__ float gelu_erf(float x){
    return 0.5f * x * (1.0f + erff(x * 0.70710678118654752f));
}
// bf16 helpers
__device__ __forceinline__ float bflo(uintT u){ return __uint_as_float(u << 16); }
__device__ __forceinline__ float bfhi(uintT u){ return __uint_as_float(u & 0xFFFF0000u); }
__device__ __forceinline__ ushortT f2bf(float f){
    uintT u = __float_as_uint(f);
    return (ushortT)((u + 0x7FFFu + ((u >> 16) & 1u)) >> 16);   // RNE
}
// truncation split: f = hi + lo_resid; both bf16 (trunc). Residual error ~2^-16 rel.
__device__ __forceinline__ void split_bf16(float f, ushortT& hi, ushortT& lo){
    uintT u = __float_as_uint(f);
    hi = (ushortT)(u >> 16);
    float fhi = __uint_as_float(u & 0xFFFF0000u);
    lo = (ushortT)(__float_as_uint(f - fhi) >> 16);
}

// ---------------- weight prepack + gcur zero ----------------
__global__ __launch_bounds__(256) void k_packW(const float* __restrict__ Wa,
                                               const float* __restrict__ Wb,
                                               const float* __restrict__ Wc,
                                               const float* __restrict__ Wd,
                                               const float* __restrict__ We,
                                               ushortT* __restrict__ Wp,
                                               int* __restrict__ gcur){
    int l = blockIdx.x;
    int t = threadIdx.x;
    if (l < 4){
        const float* W = (l==0) ? Wa : (l==1) ? Wb : (l==2) ? Wc : Wd;
        ushortT* hiP = Wp + (size_t)l*2*16384;
        ushortT* loP = hiP + 16384;
        for (int idx = t; idx < 16384; idx += 256){
            int k = idx >> 7, n = idx & 127;
            ushortT hi, lo;
            split_bf16(W[idx], hi, lo);
            int kc = k >> 5, quad = (k >> 3) & 3, j = k & 7;
            int nt = n >> 4, lane = (n & 15) + (quad << 4);
            int off = ((kc*8 + nt)*64 + lane)*8 + j;
            hiP[off] = hi;
            loP[off] = lo;
        }
    } else {
        if (t < NBUCKET) gcur[t] = 0;
        ushortT* hiP = Wp + (size_t)4*2*16384;
        ushortT* loP = hiP + 2048;
        for (int idx = t; idx < 2048; idx += 256){
            int k = idx >> 4, n = idx & 15;
            ushortT hi, lo;
            split_bf16(We[idx], hi, lo);
            int kc = k >> 5, quad = (k >> 3) & 3, j = k & 7;
            int lane = n + (quad << 4);
            int off = (kc*64 + lane)*8 + j;
            hiP[off] = hi;
            loP[off] = lo;
        }
    }
}

// ---------------- CSR build ----------------
__global__ __launch_bounds__(256) void k_bucketA(const int* __restrict__ ei,
                                                 int* __restrict__ gcur,
                                                 uintT* __restrict__ bucket){
    __shared__ int hist[NBUCKET];
    __shared__ int base[NBUCKET];
    int t = threadIdx.x;
    if (t < NBUCKET) hist[t] = 0;
    __syncthreads();
    int e0 = blockIdx.x * EPWA;
    int cr_c[12], cr_r[12];
    #pragma unroll
    for (int p = 0; p < 12; p++){
        int e = e0 + p*256 + t;
        if (e < NEDGES){
            cr_r[p] = ei[e];
            cr_c[p] = ei[NEDGES + e];
            atomicAdd(&hist[cr_c[p] >> 8], 1);
        } else cr_c[p] = -1;
    }
    __syncthreads();
    if (t < NBUCKET){
        base[t] = atomicAdd(&gcur[t], hist[t]);
        hist[t] = 0;   // reuse as local cursor
    }
    __syncthreads();
    #pragma unroll
    for (int p = 0; p < 12; p++){
        int c = cr_c[p];
        if (c >= 0){
            int b = c >> 8;
            int lp = atomicAdd(&hist[b], 1);
            bucket[(size_t)b*BCAP + base[b] + lp] = ((uintT)c << 16) | (uintT)cr_r[p];
        }
    }
}

__global__ __launch_bounds__(256) void k_bucketB(const int* __restrict__ gcur,
                                                 const uintT* __restrict__ bucket,
                                                 int* __restrict__ offs,
                                                 float* __restrict__ dinv,
                                                 ushortT* __restrict__ csr2){
    __shared__ int sm[256];
    __shared__ int hist[256];
    __shared__ int lcur[256];
    int b = blockIdx.x;
    int t = threadIdx.x;
    int n0 = b << 8;

    int gv = (t < NBUCKET) ? gcur[t] : 0;
    sm[t] = gv;
    __syncthreads();
    for (int off = 1; off < 256; off <<= 1){
        int tv = (t >= off) ? sm[t-off] : 0;
        __syncthreads();
        sm[t] += tv;
        __syncthreads();
    }
    __shared__ int bbase_s;
    if (t == b) bbase_s = sm[t] - gv;
    hist[t] = 0;
    __syncthreads();
    int bbase = bbase_s;
    int count = gcur[b];
    const uintT* src = bucket + (size_t)b*BCAP;

    for (int i = t; i < count; i += 256)
        atomicAdd(&hist[(src[i] >> 16) & 255], 1);
    __syncthreads();

    int v = hist[t];
    sm[t] = v;
    __syncthreads();
    for (int off = 1; off < 256; off <<= 1){
        int tv = (t >= off) ? sm[t-off] : 0;
        __syncthreads();
        sm[t] += tv;
        __syncthreads();
    }
    int excl = bbase + sm[t] - v;
    int node = n0 + t;
    if (node <= NNODES) offs[node] = excl;
    if (node < NNODES) dinv[node] = rsqrtf((float)(v + 1));
    if (b == NBUCKET-1 && t == 255) offs[NNODES] = NEDGES;
    lcur[t] = excl;
    __syncthreads();

    for (int i = t; i < count; i += 256){
        uintT e = src[i];
        int pos = atomicAdd(&lcur[(e >> 16) & 255], 1);
        csr2[pos] = (ushortT)(e & 0xFFFFu);
    }
}

// ---------------- MFMA GEMM (fp32 A, layer 1): [N,128]x[128,128] split-bf16 x3 -------
__global__ __launch_bounds__(256) void k_mfma_f32(const float* __restrict__ A,
                                                  const ushortT* __restrict__ Wp,
                                                  const float* __restrict__ scale,
                                                  const float* __restrict__ dinv,
                                                  ushortT* __restrict__ Yb){
    __shared__ float As[64*132];
    int t = threadIdx.x;
    int wave = t >> 6, lane = t & 63;
    int r = lane & 15, quad = lane >> 4;
    int row0 = blockIdx.x*64;
    int m0 = row0 + wave*16;
    const ushortT* WpLo = Wp + 16384;

    #pragma unroll
    for (int p = 0; p < 8; p++){
        int idx = p*256 + t;
        int rr = idx >> 5;
        int c4 = idx & 31;
        int gr = row0 + rr;
        float4 v = make_float4(0.f,0.f,0.f,0.f);
        if (gr < NNODES) v = *(const float4*)&A[(size_t)gr*FDIM + c4*4];
        float4 s = *(const float4*)&scale[c4*4];
        v.x*=s.x; v.y*=s.y; v.z*=s.z; v.w*=s.w;
        *(float4*)&As[rr*132 + c4*4] = v;
    }
    __syncthreads();

    floatx4 acc[8];
    #pragma unroll
    for (int nt = 0; nt < 8; nt++) acc[nt] = (floatx4){0.f,0.f,0.f,0.f};

    int arl = wave*16 + r;
    #pragma unroll
    for (int kc = 0; kc < 4; kc++){
        int kb = kc*32 + quad*8;
        float4 a0 = *(const float4*)&As[arl*132 + kb];
        float4 a1 = *(const float4*)&As[arl*132 + kb + 4];
        float av[8] = {a0.x, a0.y, a0.z, a0.w, a1.x, a1.y, a1.z, a1.w};
        short8 ahi, alo;
        #pragma unroll
        for (int e = 0; e < 8; e++){
            ushortT h, l;
            split_bf16(av[e], h, l);
            ahi[e] = (short)h;
            alo[e] = (short)l;
        }
        #pragma unroll
        for (int nt = 0; nt < 8; nt++){
            size_t boff = (size_t)(((kc*8 + nt)*64 + lane))*8;
            short8 bhi = *(const short8*)&Wp[boff];
            short8 blo = *(const short8*)&WpLo[boff];
            acc[nt] = __builtin_amdgcn_mfma_f32_16x16x32_bf16(ahi, bhi, acc[nt], 0, 0, 0);
            acc[nt] = __builtin_amdgcn_mfma_f32_16x16x32_bf16(alo, bhi, acc[nt], 0, 0, 0);
            acc[nt] = __builtin_amdgcn_mfma_f32_16x16x32_bf16(ahi, blo, acc[nt], 0, 0, 0);
        }
    }

    int orow0 = m0 + quad*4;
    float4 dv = *(const float4*)&dinv[orow0];
    float dva[4] = {dv.x, dv.y, dv.z, dv.w};
    #pragma unroll
    for (int nt = 0; nt < 8; nt++){
        int n = nt*16 + r;
        int chunk = n >> 6, o = n & 63;
        #pragma unroll
        for (int reg = 0; reg < 4; reg++){
            int orow = orow0 + reg;
            if (orow < NNODES){
                float v = acc[nt][reg] * dva[reg];
                Yb[((size_t)chunk*NNODES + orow)*64 + o] = f2bf(v);
            }
        }
    }
}

// ---------------- MFMA GEMM (bf16 A, layers 2/3): zero-LDS, split-W x2 --------------
__global__ __launch_bounds__(256) void k_mfma_b16(const ushortT* __restrict__ Ab,
                                                  const ushortT* __restrict__ Wp,
                                                  const float* __restrict__ dinv,
                                                  ushortT* __restrict__ Yb){
    int t = threadIdx.x;
    int wave = t >> 6, lane = t & 63;
    int r = lane & 15, quad = lane >> 4;
    int m0 = blockIdx.x*64 + wave*16;
    int arow = m0 + r;
    if (arow >= NNODES) arow = NNODES - 1;
    const ushortT* WpLo = Wp + 16384;

    floatx4 acc[8];
    #pragma unroll
    for (int nt = 0; nt < 8; nt++) acc[nt] = (floatx4){0.f,0.f,0.f,0.f};

    short8 afr[4];
    #pragma unroll
    for (int kc = 0; kc < 4; kc++)
        afr[kc] = *(const short8*)&Ab[(size_t)arow*FDIM + kc*32 + quad*8];

    #pragma unroll
    for (int kc = 0; kc < 4; kc++){
        #pragma unroll
        for (int nt = 0; nt < 8; nt++){
            size_t boff = (size_t)(((kc*8 + nt)*64 + lane))*8;
            short8 bhi = *(const short8*)&Wp[boff];
            short8 blo = *(const short8*)&WpLo[boff];
            acc[nt] = __builtin_amdgcn_mfma_f32_16x16x32_bf16(afr[kc], bhi, acc[nt], 0, 0, 0);
            acc[nt] = __builtin_amdgcn_mfma_f32_16x16x32_bf16(afr[kc], blo, acc[nt], 0, 0, 0);
        }
    }

    int orow0 = m0 + quad*4;
    float4 dv = *(const float4*)&dinv[orow0];
    float dva[4] = {dv.x, dv.y, dv.z, dv.w};
    #pragma unroll
    for (int nt = 0; nt < 8; nt++){
        int n = nt*16 + r;
        int chunk = n >> 6, o = n & 63;
        #pragma unroll
        for (int reg = 0; reg < 4; reg++){
            int orow = orow0 + reg;
            if (orow < NNODES){
                float v = acc[nt][reg] * dva[reg];
                Yb[((size_t)chunk*NNODES + orow)*64 + o] = f2bf(v);
            }
        }
    }
}

// ---------------- fused final: out = gelu(H@lw1+lb1)@lw2 + lb2 ----------------------
__global__ __launch_bounds__(256) void k_mfma_final(const ushortT* __restrict__ Ab,
                                                    const ushortT* __restrict__ Wp1,
                                                    const ushortT* __restrict__ Wp2,
                                                    const float* __restrict__ lb1,
                                                    const float* __restrict__ lb2,
                                                    float* __restrict__ out){
    __shared__ ushortT Ls[64*136];
    int t = threadIdx.x;
    int wave = t >> 6, lane = t & 63;
    int r = lane & 15, quad = lane >> 4;
    int row0 = blockIdx.x*64;
    int m0 = row0 + wave*16;
    int arow = m0 + r;
    if (arow >= NNODES) arow = NNODES - 1;
    const ushortT* Wp1Lo = Wp1 + 16384;
    const ushortT* Wp2Lo = Wp2 + 2048;

    floatx4 acc[8];
    #pragma unroll
    for (int nt = 0; nt < 8; nt++) acc[nt] = (floatx4){0.f,0.f,0.f,0.f};

    short8 afr[4];
    #pragma unroll
    for (int kc = 0; kc < 4; kc++)
        afr[kc] = *(const short8*)&Ab[(size_t)arow*FDIM + kc*32 + quad*8];

    #pragma unroll
    for (int kc = 0; kc < 4; kc++){
        #pragma unroll
        for (int nt = 0; nt < 8; nt++){
            size_t boff = (size_t)(((kc*8 + nt)*64 + lane))*8;
            short8 bhi = *(const short8*)&Wp1[boff];
            short8 blo = *(const short8*)&Wp1Lo[boff];
            acc[nt] = __builtin_amdgcn_mfma_f32_16x16x32_bf16(afr[kc], bhi, acc[nt], 0, 0, 0);
            acc[nt] = __builtin_amdgcn_mfma_f32_16x16x32_bf16(afr[kc], blo, acc[nt], 0, 0, 0);
        }
    }

    int lrow0 = wave*16 + quad*4;
    #pragma unroll
    for (int nt = 0; nt < 8; nt++){
        int n = nt*16 + r;
        float bv = lb1[n];
        #pragma unroll
        for (int reg = 0; reg < 4; reg++){
            Ls[(lrow0 + reg)*136 + n] = f2bf(gelu_erf(acc[nt][reg] + bv));
        }
    }
    __syncthreads();

    floatx4 acc2 = (floatx4){0.f,0.f,0.f,0.f};
    #pragma unroll
    for (int kc = 0; kc < 4; kc++){
        short8 a2 = *(const short8*)&Ls[(wave*16 + r)*136 + kc*32 + quad*8];
        short8 bhi = *(const short8*)&Wp2[(size_t)(kc*64 + lane)*8];
        short8 blo = *(const short8*)&Wp2Lo[(size_t)(kc*64 + lane)*8];
        acc2 = __builtin_amdgcn_mfma_f32_16x16x32_bf16(a2, bhi, acc2, 0, 0, 0);
        acc2 = __builtin_amdgcn_mfma_f32_16x16x32_bf16(a2, blo, acc2, 0, 0, 0);
    }
    float bv2 = lb2[r];
    #pragma unroll
    for (int reg = 0; reg < 4; reg++){
        int orow = m0 + quad*4 + reg;
        if (orow < NNODES)
            out[(size_t)orow*16 + r] = acc2[reg] + bv2;
    }
}

// ---------------- sharded aggregation: 2 chunks x 64 feats, 32 lanes/node -----------
__global__ __launch_bounds__(256) void k_aggregate(const ushortT* __restrict__ Yt,
                                                   const float* __restrict__ dinv,
                                                   const int* __restrict__ offs,
                                                   const ushortT* __restrict__ csr2,
                                                   const float* __restrict__ bias,
                                                   ushortT* __restrict__ Hout){
    int bid = blockIdx.x;
    int chunk = bid & 1;
    int node = (bid >> 1) * 8 + (threadIdx.x >> 5);
    int lane = threadIdx.x & 31;
    const uintT* Yc = (const uintT*)Yt + (size_t)chunk * NNODES * 32;

    uintT a0 = Yc[node*32 + lane];
    float2 acc;
    acc.x = bflo(a0);
    acc.y = bfhi(a0);
    int e0 = offs[node], e1 = offs[node+1];
    int e = e0;
    for (; e + 7 < e1; e += 8){
        int r0 = csr2[e+0];
        int r1 = csr2[e+1];
        int r2 = csr2[e+2];
        int r3 = csr2[e+3];
        int r4 = csr2[e+4];
        int r5 = csr2[e+5];
        int r6 = csr2[e+6];
        int r7 = csr2[e+7];
        uintT q0 = Yc[r0*32 + lane];
        uintT q1 = Yc[r1*32 + lane];
        uintT q2 = Yc[r2*32 + lane];
        uintT q3 = Yc[r3*32 + lane];
        uintT q4 = Yc[r4*32 + lane];
        uintT q5 = Yc[r5*32 + lane];
        uintT q6 = Yc[r6*32 + lane];
        uintT q7 = Yc[r7*32 + lane];
        acc.x += bflo(q0); acc.y += bfhi(q0);
        acc.x += bflo(q1); acc.y += bfhi(q1);
        acc.x += bflo(q2); acc.y += bfhi(q2);
        acc.x += bflo(q3); acc.y += bfhi(q3);
        acc.x += bflo(q4); acc.y += bfhi(q4);
        acc.x += bflo(q5); acc.y += bfhi(q5);
        acc.x += bflo(q6); acc.y += bfhi(q6);
        acc.x += bflo(q7); acc.y += bfhi(q7);
    }
    for (; e + 1 < e1; e += 2){
        int r0 = csr2[e], r1 = csr2[e+1];
        uintT q0 = Yc[r0*32 + lane];
        uintT q1 = Yc[r1*32 + lane];
        acc.x += bflo(q0); acc.y += bfhi(q0);
        acc.x += bflo(q1); acc.y += bfhi(q1);
    }
    if (e < e1){
        uintT q = Yc[csr2[e]*32 + lane];
        acc.x += bflo(q); acc.y += bfhi(q);
    }
    float dc = dinv[node];
    float2 bv = ((const float2*)bias)[chunk*32 + lane];
    acc.x = gelu_erf(fmaf(dc, acc.x, bv.x));
    acc.y = gelu_erf(fmaf(dc, acc.y, bv.y));
    uintT packed = (uintT)f2bf(acc.x) | ((uintT)f2bf(acc.y) << 16);
    *(uintT*)&Hout[(size_t)node*FDIM + chunk*64 + lane*2] = packed;
}

extern "C" void kernel_launch(void* const* d_in, const int* in_sizes, int n_in,
                              void* d_out, int out_size, void* d_ws, size_t ws_size,
                              hipStream_t stream) {
    const float* x    = (const float*)d_in[0];
    const int*   ei   = (const int*)d_in[1];
    const float* imp  = (const float*)d_in[2];
    const float* W1   = (const float*)d_in[3];
    const float* b1   = (const float*)d_in[4];
    const float* W2   = (const float*)d_in[5];
    const float* b2   = (const float*)d_in[6];
    const float* W3   = (const float*)d_in[7];
    const float* b3   = (const float*)d_in[8];
    const float* lw1  = (const float*)d_in[9];
    const float* lb1  = (const float*)d_in[10];
    const float* lw2  = (const float*)d_in[11];
    const float* lb2  = (const float*)d_in[12];
    float* out = (float*)d_out;

    // workspace layout (units of 4 bytes)
    int*   offs   = (int*)d_ws;                          // 50001 (pad to 50048)
    int*   gcur   = (int*)d_ws + 50048;                  // 196 (pad to 50304)
    float* dinv   = (float*)d_ws + 50304;                // 50000 (pad to 100480)
    ushortT* csr2 = (ushortT*)((int*)d_ws + 100480);     // 800000 ushort (1.6 MB)
    uintT* bucket = (uintT*)((int*)d_ws + 500480);       // 196*6144 uint (4.8 MB)
    ushortT* Wp   = (ushortT*)((int*)d_ws + 1704704);    // 4*32768 + 4096 ushort (~270 KB)
    ushortT* bufYt= (ushortT*)((int*)d_ws + 1772544);    // 50000*128 bf16 2-chunk-transposed
    ushortT* bufH = (ushortT*)((int*)d_ws + 4972544);    // 50000*128 bf16 row-major

    dim3 B(256);
    // ---- weight prepack (+gcur zero) + CSR build ----
    k_packW  <<<5, B, 0, stream>>>(W1, W2, W3, lw1, lw2, Wp, gcur);
    k_bucketA<<<ABLK, B, 0, stream>>>(ei, gcur, bucket);
    k_bucketB<<<NBUCKET, B, 0, stream>>>(gcur, bucket, offs, dinv, csr2);

    // ---- conv layers ----
    k_mfma_f32 <<<MGRID, B, 0, stream>>>(x, Wp + 0*32768, imp, dinv, bufYt);
    k_aggregate<<<(NNODES/8)*2, B, 0, stream>>>(bufYt, dinv, offs, csr2, b1, bufH);
    k_mfma_b16 <<<MGRID, B, 0, stream>>>(bufH, Wp + 1*32768, dinv, bufYt);
    k_aggregate<<<(NNODES/8)*2, B, 0, stream>>>(bufYt, dinv, offs, csr2, b2, bufH);
    k_mfma_b16 <<<MGRID, B, 0, stream>>>(bufH, Wp + 2*32768, dinv, bufYt);
    k_aggregate<<<(NNODES/8)*2, B, 0, stream>>>(bufYt, dinv, offs, csr2, b3, bufH);

    // ---- out = gelu(H@lw1+lb1)@lw2 + lb2 (fused) ----
    k_mfma_final<<<MGRID, B, 0, stream>>>(bufH, Wp + 3*32768, Wp + 4*32768, lb1, lb2, out);
}